// Round 1
// baseline (1138.508 us; speedup 1.0000x reference)
//
#include <hip/hip_runtime.h>
#include <math.h>

#define NN 50000
#define NE 800000

__device__ __forceinline__ float lrelu(float x, float s) { return x >= 0.f ? x : s * x; }

// Per-node GAT1 head-0: z1[n,80], el1[n], er1[n]
__global__ void k_z1(const float* __restrict__ feat, const float* __restrict__ W,
                     const float* __restrict__ al, const float* __restrict__ ar,
                     float* __restrict__ z1, float* __restrict__ el1, float* __restrict__ er1) {
    __shared__ float sW[240], sAl[80], sAr[80];
    for (int t = threadIdx.x; t < 80; t += blockDim.x) {
        sW[t]       = W[t];         // c=0, head0 cols 0..79 of [3,160]
        sW[80 + t]  = W[160 + t];   // c=1
        sW[160 + t] = W[320 + t];   // c=2
        sAl[t] = al[t];
        sAr[t] = ar[t];
    }
    __syncthreads();
    int n = blockIdx.x * blockDim.x + threadIdx.x;
    if (n >= NN) return;
    float f0 = feat[n * 3 + 0], f1 = feat[n * 3 + 1], f2 = feat[n * 3 + 2];
    float el = 0.f, er = 0.f;
    float* zr = z1 + (size_t)n * 80;
    #pragma unroll
    for (int f = 0; f < 80; ++f) {
        float z = f0 * sW[f] + f1 * sW[80 + f] + f2 * sW[160 + f];
        zr[f] = z;
        el += z * sAl[f];
        er += z * sAr[f];
    }
    el1[n] = el;
    er1[n] = er;
}

// Per-edge: w = exp(lrelu(el[src]+er[dst], 0.2)); denom[dst] += w
__global__ void k_edge_a(const int* __restrict__ src, const int* __restrict__ dst,
                         const float* __restrict__ el, const float* __restrict__ er,
                         float* __restrict__ w, float* __restrict__ denom) {
    int e = blockIdx.x * blockDim.x + threadIdx.x;
    if (e >= NE) return;
    int s = src[e], d = dst[e];
    float x = el[s] + er[d];
    float wv = __expf(lrelu(x, 0.2f));
    w[e] = wv;
    atomicAdd(&denom[d], wv);
}

// Per-(edge,f): rst_un[dst,f] += z[src,f] * w[e]
template <int F>
__global__ void k_edge_b(const int* __restrict__ src, const int* __restrict__ dst,
                         const float* __restrict__ w, const float* __restrict__ z,
                         float* __restrict__ rst) {
    unsigned int idx = blockIdx.x * blockDim.x + threadIdx.x;
    if (idx >= (unsigned int)NE * F) return;
    unsigned int e = idx / F;
    unsigned int f = idx - e * F;
    int s = src[e], d = dst[e];
    atomicAdd(&rst[(size_t)d * F + f], z[(size_t)s * F + f] * w[e]);
}

// Per-node: g1 = relu(rst1/denom1 + b1); z2 = g1 @ W2h0 [80,30]; el2, er2
__global__ void k_node1(const float* __restrict__ rst1, const float* __restrict__ denom1,
                        const float* __restrict__ b1, const float* __restrict__ W2,
                        const float* __restrict__ al2, const float* __restrict__ ar2,
                        float* __restrict__ z2, float* __restrict__ el2, float* __restrict__ er2) {
    __shared__ float sW[80 * 30], sB[80], sAl[30], sAr[30];
    for (int t = threadIdx.x; t < 2400; t += blockDim.x)
        sW[t] = W2[(t / 30) * 60 + (t % 30)];  // head2=0 cols 0..29 of [80,60]
    for (int t = threadIdx.x; t < 80; t += blockDim.x) sB[t] = b1[t];
    for (int t = threadIdx.x; t < 30; t += blockDim.x) { sAl[t] = al2[t]; sAr[t] = ar2[t]; }
    __syncthreads();
    int n = blockIdx.x * blockDim.x + threadIdx.x;
    if (n >= NN) return;
    float d = denom1[n];
    float inv = (d != 0.f) ? 1.f / d : 0.f;  // no-in-edge node: rst=0 -> relu(b1)
    float acc[30];
    #pragma unroll
    for (int j = 0; j < 30; ++j) acc[j] = 0.f;
    const float* rr = rst1 + (size_t)n * 80;
    for (int f = 0; f < 80; ++f) {
        float g = rr[f] * inv + sB[f];
        g = g > 0.f ? g : 0.f;
        #pragma unroll
        for (int j = 0; j < 30; ++j) acc[j] += g * sW[f * 30 + j];
    }
    float el = 0.f, er = 0.f;
    float* zr = z2 + (size_t)n * 30;
    #pragma unroll
    for (int j = 0; j < 30; ++j) {
        zr[j] = acc[j];
        el += acc[j] * sAl[j];
        er += acc[j] * sAr[j];
    }
    el2[n] = el;
    er2[n] = er;
}

// Sum over nodes of rst2/denom2 -> a_acc[30] (mean and +b2 applied in k_final)
__global__ void k_reduce(const float* __restrict__ rst2, const float* __restrict__ denom2,
                         float* __restrict__ a_acc) {
    __shared__ float s[30];
    if (threadIdx.x < 30) s[threadIdx.x] = 0.f;
    __syncthreads();
    float acc[30];
    #pragma unroll
    for (int j = 0; j < 30; ++j) acc[j] = 0.f;
    for (int n = blockIdx.x * blockDim.x + threadIdx.x; n < NN; n += gridDim.x * blockDim.x) {
        float d = denom2[n];
        if (d != 0.f) {
            float inv = 1.f / d;
            const float* rr = rst2 + (size_t)n * 30;
            #pragma unroll
            for (int j = 0; j < 30; ++j) acc[j] += rr[j] * inv;
        }
    }
    #pragma unroll
    for (int j = 0; j < 30; ++j) atomicAdd(&s[j], acc[j]);
    __syncthreads();
    if (threadIdx.x < 30) atomicAdd(&a_acc[threadIdx.x], s[threadIdx.x]);
}

// Image branch: emb = x@W_lin1 [2,30]; h = lrelu(Wc1@emb); h2 = lrelu(Wc2@h) [30]
__global__ void k_img(const float* __restrict__ x, const float* __restrict__ W1,
                      const float* __restrict__ Wc1, const float* __restrict__ Wc2,
                      float* __restrict__ h2out) {
    __shared__ float part[240];
    __shared__ float emb[60];
    __shared__ float hh[80 * 30];
    int t = threadIdx.x;  // 256 threads
    if (t < 240) {
        int g = t / 120, k = (t / 4) % 30, q = t % 4;
        float acc = 0.f;
        const float* xp = x + g * 4096 + q * 1024;
        for (int c = 0; c < 1024; ++c) acc += xp[c] * W1[(q * 1024 + c) * 30 + k];
        part[t] = acc;
    }
    __syncthreads();
    if (t < 60) {
        int g = t / 30, k = t % 30;
        int b = g * 120 + k * 4;
        emb[t] = part[b] + part[b + 1] + part[b + 2] + part[b + 3];
    }
    __syncthreads();
    for (int p = t; p < 2400; p += 256) {
        int i = p / 30, j = p % 30;
        float v = Wc1[i * 2 + 0] * emb[j] + Wc1[i * 2 + 1] * emb[30 + j];
        hh[p] = lrelu(v, 0.01f);
    }
    __syncthreads();
    if (t < 30) {
        float acc = 0.f;
        for (int i = 0; i < 80; ++i) acc += Wc2[i] * hh[i * 30 + t];
        h2out[t] = lrelu(acc, 0.01f);
    }
}

// Final head: gr, hc, two tiny matmuls, log_softmax
__global__ void k_final(const float* __restrict__ a_acc, const float* __restrict__ b2,
                        const float* __restrict__ Wg1, const float* __restrict__ bg1,
                        const float* __restrict__ h2, const float* __restrict__ vocab,
                        const float* __restrict__ W2, const float* __restrict__ W3,
                        float* __restrict__ out, int out_size) {
    __shared__ float g[60];
    __shared__ float hc[70];
    __shared__ float tt[80];
    __shared__ float lp[2];
    int t = threadIdx.x;  // 128 threads
    if (t < 60) g[t] = a_acc[t] * (1.f / NN) + b2[t % 30];
    __syncthreads();
    if (t < 30) {
        float acc = bg1[t];
        for (int j = 0; j < 60; ++j) acc += g[j] * Wg1[j * 30 + t];
        hc[t] = acc;
        hc[30 + t] = h2[t];
        if (t < 10) hc[60 + t] = vocab[t];
    }
    __syncthreads();
    if (t < 80) {
        float acc = 0.f;
        for (int q = 0; q < 70; ++q) acc += hc[q] * W2[q * 80 + t];
        tt[t] = acc;
    }
    __syncthreads();
    if (t < 2) {
        float acc = 0.f;
        for (int p = 0; p < 80; ++p) acc += tt[p] * W3[p * 2 + t];
        lp[t] = acc;
    }
    __syncthreads();
    if (t == 0) {
        float m = fmaxf(lp[0], lp[1]);
        float lse = m + logf(expf(lp[0] - m) + expf(lp[1] - m));
        out[0] = lp[0] - lse;
        out[1] = lp[1] - lse;
    }
    for (int i = 2 + t; i < out_size; i += blockDim.x) out[i] = 0.f;
}

extern "C" void kernel_launch(void* const* d_in, const int* in_sizes, int n_in,
                              void* d_out, int out_size, void* d_ws, size_t ws_size,
                              hipStream_t stream) {
    const float* x        = (const float*)d_in[0];
    const float* vocab    = (const float*)d_in[1];
    const float* nodef    = (const float*)d_in[2];
    const int*   src      = (const int*)d_in[3];
    const int*   dst      = (const int*)d_in[4];
    const float* W_lin1   = (const float*)d_in[5];
    const float* Wc1      = (const float*)d_in[6];
    const float* Wc2      = (const float*)d_in[7];
    const float* gat1_W   = (const float*)d_in[8];
    const float* gat1_al  = (const float*)d_in[9];
    const float* gat1_ar  = (const float*)d_in[10];
    const float* gat1_b   = (const float*)d_in[11];
    const float* gat2_W   = (const float*)d_in[12];
    const float* gat2_al  = (const float*)d_in[13];
    const float* gat2_ar  = (const float*)d_in[14];
    const float* gat2_b   = (const float*)d_in[15];
    const float* Wg1      = (const float*)d_in[16];
    const float* bg1      = (const float*)d_in[17];
    const float* W2       = (const float*)d_in[18];
    const float* W3       = (const float*)d_in[19];

    float* w = (float*)d_ws;
    size_t off = 0;
    auto alloc = [&](size_t n) { size_t o = off; off += (n + 63) & ~(size_t)63; return o; };
    size_t o_h2   = alloc(30);
    size_t o_acc  = alloc(60);
    size_t o_z1   = alloc((size_t)NN * 80);
    size_t o_rst1 = alloc((size_t)NN * 80);  // zero-region start
    size_t o_den1 = alloc(NN);
    size_t o_rst2 = alloc((size_t)NN * 30);
    size_t o_den2 = alloc(NN);
    size_t o_zend = off;                      // zero-region end
    size_t o_el1  = alloc(NN);
    size_t o_er1  = alloc(NN);
    size_t o_w1   = alloc(NE);
    size_t o_z2   = alloc((size_t)NN * 30);
    size_t o_el2  = alloc(NN);
    size_t o_er2  = alloc(NN);
    size_t o_w2   = alloc(NE);
    (void)ws_size; (void)in_sizes; (void)n_in;

    hipMemsetAsync(w + o_acc, 0, 64 * sizeof(float), stream);
    k_img<<<1, 256, 0, stream>>>(x, W_lin1, Wc1, Wc2, w + o_h2);

    for (int i = 0; i < 2; ++i) {
        const float* feat = nodef + (size_t)i * NN * 3;
        const int* s = src + (size_t)i * NE;
        const int* d = dst + (size_t)i * NE;
        hipMemsetAsync(w + o_rst1, 0, (o_zend - o_rst1) * sizeof(float), stream);
        k_z1<<<(NN + 255) / 256, 256, 0, stream>>>(feat, gat1_W, gat1_al, gat1_ar,
                                                   w + o_z1, w + o_el1, w + o_er1);
        k_edge_a<<<(NE + 255) / 256, 256, 0, stream>>>(s, d, w + o_el1, w + o_er1,
                                                       w + o_w1, w + o_den1);
        k_edge_b<80><<<(NE * 80 + 255) / 256, 256, 0, stream>>>(s, d, w + o_w1, w + o_z1,
                                                                w + o_rst1);
        k_node1<<<(NN + 255) / 256, 256, 0, stream>>>(w + o_rst1, w + o_den1, gat1_b, gat2_W,
                                                      gat2_al, gat2_ar,
                                                      w + o_z2, w + o_el2, w + o_er2);
        k_edge_a<<<(NE + 255) / 256, 256, 0, stream>>>(s, d, w + o_el2, w + o_er2,
                                                       w + o_w2, w + o_den2);
        k_edge_b<30><<<(NE * 30 + 255) / 256, 256, 0, stream>>>(s, d, w + o_w2, w + o_z2,
                                                                w + o_rst2);
        k_reduce<<<512, 256, 0, stream>>>(w + o_rst2, w + o_den2, w + o_acc + i * 30);
    }

    k_final<<<1, 128, 0, stream>>>(w + o_acc, gat2_b, Wg1, bg1, w + o_h2, vocab,
                                   W2, W3, (float*)d_out, out_size);
}

// Round 2
// 695.540 us; speedup vs baseline: 1.6369x; 1.6369x over previous
//
#include <hip/hip_runtime.h>
#include <math.h>

#define NN 50000
#define NE 800000

__device__ __forceinline__ float lrelu(float x, float s) { return x >= 0.f ? x : s * x; }

// prep[0..79]=u (W2h0@al2), prep[80..159]=v (W2h0@ar2), prep[160..162]=wl1, prep[163..165]=wr1
__global__ void k_prep(const float* __restrict__ W1, const float* __restrict__ al1,
                       const float* __restrict__ ar1, const float* __restrict__ W2,
                       const float* __restrict__ al2, const float* __restrict__ ar2,
                       float* __restrict__ prep) {
    int t = threadIdx.x;  // 128
    if (t < 80) {
        float u = 0.f, v = 0.f;
        for (int j = 0; j < 30; ++j) {
            float w = W2[t * 60 + j];  // head0 cols of [80, 60]
            u += w * al2[j];           // al2 row 0 of [2,30]
            v += w * ar2[j];
        }
        prep[t] = u;
        prep[80 + t] = v;
    } else if (t < 83) {
        int c = t - 80;
        float a = 0.f, b = 0.f;
        for (int f = 0; f < 80; ++f) {
            float w = W1[c * 160 + f];  // head0 cols of [3, 160]
            a += w * al1[f];            // al1 row 0 of [2,80]
            b += w * ar1[f];
        }
        prep[160 + c] = a;
        prep[163 + c] = b;
    }
}

// er1[g][n] = feat[g][n] . wr1
__global__ void k_er1(const float* __restrict__ nodef, const float* __restrict__ prep,
                      float* __restrict__ er1) {
    int g = blockIdx.y;
    int n = blockIdx.x * blockDim.x + threadIdx.x;
    if (n >= NN) return;
    const float* f = nodef + ((size_t)g * NN + n) * 3;
    er1[g * NN + n] = f[0] * prep[163] + f[1] * prep[164] + f[2] * prep[165];
}

// Per edge: w1 = exp(lrelu(feat[s].wl1 + er1[d])); facc4[d] += {w1*f0, w1*f1, w1*f2, w1}
__global__ void k_e1(const int* __restrict__ src, const int* __restrict__ dst,
                     const float* __restrict__ nodef, const float* __restrict__ prep,
                     const float* __restrict__ er1, float* __restrict__ facc4) {
    int g = blockIdx.y;
    int e = blockIdx.x * blockDim.x + threadIdx.x;
    if (e >= NE) return;
    int s = src[(size_t)g * NE + e], d = dst[(size_t)g * NE + e];
    const float* f = nodef + ((size_t)g * NN + s) * 3;
    float f0 = f[0], f1 = f[1], f2 = f[2];
    float el = f0 * prep[160] + f1 * prep[161] + f2 * prep[162];
    float wv = __expf(lrelu(el + er1[g * NN + d], 0.2f));
    float* fa = facc4 + ((size_t)g * NN + d) * 4;
    atomicAdd(fa + 0, wv * f0);
    atomicAdd(fa + 1, wv * f1);
    atomicAdd(fa + 2, wv * f2);
    atomicAdd(fa + 3, wv);
}

// Per node: g1 = relu(facc.xyz/facc.w @ W1h0 + b1); el2 = g1.u, er2 = g1.v
__global__ void k_n1(const float* __restrict__ facc4, const float* __restrict__ W1,
                     const float* __restrict__ b1, const float* __restrict__ prep,
                     float* __restrict__ el2, float* __restrict__ er2) {
    __shared__ float sW[240], sB[80], sU[80], sV[80];
    for (int t = threadIdx.x; t < 80; t += blockDim.x) {
        sW[t] = W1[t];
        sW[80 + t] = W1[160 + t];
        sW[160 + t] = W1[320 + t];
        sB[t] = b1[t];
        sU[t] = prep[t];
        sV[t] = prep[80 + t];
    }
    __syncthreads();
    int g = blockIdx.y;
    int n = blockIdx.x * blockDim.x + threadIdx.x;
    if (n >= NN) return;
    float4 fa = *(const float4*)(facc4 + ((size_t)g * NN + n) * 4);
    float inv = fa.w != 0.f ? 1.f / fa.w : 0.f;
    float c0 = fa.x * inv, c1 = fa.y * inv, c2 = fa.z * inv;
    float el = 0.f, er = 0.f;
    #pragma unroll
    for (int f = 0; f < 80; ++f) {
        float gg = c0 * sW[f] + c1 * sW[80 + f] + c2 * sW[160 + f] + sB[f];
        gg = gg > 0.f ? gg : 0.f;
        el += gg * sU[f];
        er += gg * sV[f];
    }
    el2[g * NN + n] = el;
    er2[g * NN + n] = er;
}

// Per edge: w2 = exp(lrelu(el2[s]+er2[d])); den2[d] += w2; store w2
__global__ void k_e2(const int* __restrict__ src, const int* __restrict__ dst,
                     const float* __restrict__ el2, const float* __restrict__ er2,
                     float* __restrict__ w2, float* __restrict__ den2) {
    int g = blockIdx.y;
    int e = blockIdx.x * blockDim.x + threadIdx.x;
    if (e >= NE) return;
    int s = src[(size_t)g * NE + e], d = dst[(size_t)g * NE + e];
    float wv = __expf(lrelu(el2[g * NN + s] + er2[g * NN + d], 0.2f));
    w2[(size_t)g * NE + e] = wv;
    atomicAdd(&den2[g * NN + d], wv);
}

// Per edge: q[s] += w2 / den2[d]
__global__ void k_e3(const int* __restrict__ src, const int* __restrict__ dst,
                     const float* __restrict__ w2, const float* __restrict__ den2,
                     float* __restrict__ q) {
    int g = blockIdx.y;
    int e = blockIdx.x * blockDim.x + threadIdx.x;
    if (e >= NE) return;
    int s = src[(size_t)g * NE + e], d = dst[(size_t)g * NE + e];
    atomicAdd(&q[g * NN + s], w2[(size_t)g * NE + e] / den2[g * NN + d]);
}

// A[g][0..79] = sum_n q[n] * g1[n]
__global__ void k_r(const float* __restrict__ facc4, const float* __restrict__ W1,
                    const float* __restrict__ b1, const float* __restrict__ q,
                    float* __restrict__ A) {
    __shared__ float sW[240], sB[80], sA[80];
    for (int t = threadIdx.x; t < 80; t += blockDim.x) {
        sW[t] = W1[t];
        sW[80 + t] = W1[160 + t];
        sW[160 + t] = W1[320 + t];
        sB[t] = b1[t];
        sA[t] = 0.f;
    }
    __syncthreads();
    int g = blockIdx.y;
    int base = threadIdx.x % 80;
    for (int n = blockIdx.x * blockDim.x + threadIdx.x; n < NN; n += gridDim.x * blockDim.x) {
        float qn = q[g * NN + n];
        if (qn == 0.f) continue;
        float4 fa = *(const float4*)(facc4 + ((size_t)g * NN + n) * 4);
        float inv = fa.w != 0.f ? 1.f / fa.w : 0.f;
        float c0 = fa.x * inv, c1 = fa.y * inv, c2 = fa.z * inv;
        for (int k = 0; k < 80; ++k) {
            int f = base + k;
            f = f >= 80 ? f - 80 : f;
            float gg = c0 * sW[f] + c1 * sW[80 + f] + c2 * sW[160 + f] + sB[f];
            gg = gg > 0.f ? gg : 0.f;
            atomicAdd(&sA[f], qn * gg);
        }
    }
    __syncthreads();
    for (int t = threadIdx.x; t < 80; t += blockDim.x) atomicAdd(&A[g * 80 + t], sA[t]);
}

// Image branch: emb = x@W_lin1 [2,30]; h = lrelu(Wc1@emb); h2 = lrelu(Wc2@h) [30]
__global__ void k_img(const float* __restrict__ x, const float* __restrict__ W1,
                      const float* __restrict__ Wc1, const float* __restrict__ Wc2,
                      float* __restrict__ h2out) {
    __shared__ float part[240];
    __shared__ float emb[60];
    __shared__ float hh[80 * 30];
    int t = threadIdx.x;  // 256 threads
    if (t < 240) {
        int g = t / 120, k = (t / 4) % 30, q = t % 4;
        float acc = 0.f;
        const float* xp = x + g * 4096 + q * 1024;
        for (int c = 0; c < 1024; ++c) acc += xp[c] * W1[(q * 1024 + c) * 30 + k];
        part[t] = acc;
    }
    __syncthreads();
    if (t < 60) {
        int g = t / 30, k = t % 30;
        int b = g * 120 + k * 4;
        emb[t] = part[b] + part[b + 1] + part[b + 2] + part[b + 3];
    }
    __syncthreads();
    for (int p = t; p < 2400; p += 256) {
        int i = p / 30, j = p % 30;
        float v = Wc1[i * 2 + 0] * emb[j] + Wc1[i * 2 + 1] * emb[30 + j];
        hh[p] = lrelu(v, 0.01f);
    }
    __syncthreads();
    if (t < 30) {
        float acc = 0.f;
        for (int i = 0; i < 80; ++i) acc += Wc2[i] * hh[i * 30 + t];
        h2out[t] = lrelu(acc, 0.01f);
    }
}

// Final head: a_i = A_i @ W2h0 / N + b2; gr; hc; two tiny matmuls; log_softmax
__global__ void k_final(const float* __restrict__ A, const float* __restrict__ W2g,
                        const float* __restrict__ b2, const float* __restrict__ Wg1,
                        const float* __restrict__ bg1, const float* __restrict__ h2,
                        const float* __restrict__ vocab, const float* __restrict__ W2f,
                        const float* __restrict__ W3, float* __restrict__ out, int out_size) {
    __shared__ float a[60];
    __shared__ float hc[70];
    __shared__ float tt[80];
    __shared__ float lp[2];
    int t = threadIdx.x;  // 128
    if (t < 60) {
        int i = t / 30, j = t % 30;
        float acc = 0.f;
        for (int f = 0; f < 80; ++f) acc += A[i * 80 + f] * W2g[f * 60 + j];
        a[t] = acc * (1.f / NN) + b2[j];
    }
    __syncthreads();
    if (t < 30) {
        float acc = bg1[t];
        for (int j = 0; j < 60; ++j) acc += a[j] * Wg1[j * 30 + t];
        hc[t] = acc;
        hc[30 + t] = h2[t];
        if (t < 10) hc[60 + t] = vocab[t];
    }
    __syncthreads();
    if (t < 80) {
        float acc = 0.f;
        for (int qd = 0; qd < 70; ++qd) acc += hc[qd] * W2f[qd * 80 + t];
        tt[t] = acc;
    }
    __syncthreads();
    if (t < 2) {
        float acc = 0.f;
        for (int p = 0; p < 80; ++p) acc += tt[p] * W3[p * 2 + t];
        lp[t] = acc;
    }
    __syncthreads();
    if (t == 0) {
        float m = fmaxf(lp[0], lp[1]);
        float lse = m + logf(expf(lp[0] - m) + expf(lp[1] - m));
        out[0] = lp[0] - lse;
        out[1] = lp[1] - lse;
    }
    for (int i = 2 + t; i < out_size; i += blockDim.x) out[i] = 0.f;
}

extern "C" void kernel_launch(void* const* d_in, const int* in_sizes, int n_in,
                              void* d_out, int out_size, void* d_ws, size_t ws_size,
                              hipStream_t stream) {
    const float* x        = (const float*)d_in[0];
    const float* vocab    = (const float*)d_in[1];
    const float* nodef    = (const float*)d_in[2];
    const int*   src      = (const int*)d_in[3];
    const int*   dst      = (const int*)d_in[4];
    const float* W_lin1   = (const float*)d_in[5];
    const float* Wc1      = (const float*)d_in[6];
    const float* Wc2      = (const float*)d_in[7];
    const float* gat1_W   = (const float*)d_in[8];
    const float* gat1_al  = (const float*)d_in[9];
    const float* gat1_ar  = (const float*)d_in[10];
    const float* gat1_b   = (const float*)d_in[11];
    const float* gat2_W   = (const float*)d_in[12];
    const float* gat2_al  = (const float*)d_in[13];
    const float* gat2_ar  = (const float*)d_in[14];
    const float* gat2_b   = (const float*)d_in[15];
    const float* Wg1      = (const float*)d_in[16];
    const float* bg1      = (const float*)d_in[17];
    const float* W2       = (const float*)d_in[18];
    const float* W3       = (const float*)d_in[19];
    (void)in_sizes; (void)n_in; (void)ws_size;

    float* w = (float*)d_ws;
    size_t off = 0;
    auto alloc = [&](size_t n) { size_t o = off; off += (n + 63) & ~(size_t)63; return o; };
    size_t o_h2   = alloc(32);
    size_t o_prep = alloc(192);
    size_t o_er1  = alloc(2 * NN);
    size_t o_el2  = alloc(2 * NN);
    size_t o_er2  = alloc(2 * NN);
    size_t o_w2   = alloc((size_t)2 * NE);
    size_t o_facc = alloc((size_t)2 * NN * 4);  // zero-region start
    size_t o_den2 = alloc(2 * NN);
    size_t o_q    = alloc(2 * NN);
    size_t o_A    = alloc(192);
    size_t o_zend = off;

    hipMemsetAsync(w + o_facc, 0, (o_zend - o_facc) * sizeof(float), stream);
    k_prep<<<1, 128, 0, stream>>>(gat1_W, gat1_al, gat1_ar, gat2_W, gat2_al, gat2_ar, w + o_prep);
    k_img<<<1, 256, 0, stream>>>(x, W_lin1, Wc1, Wc2, w + o_h2);

    dim3 gN((NN + 255) / 256, 2);
    dim3 gE((NE + 255) / 256, 2);
    k_er1<<<gN, 256, 0, stream>>>(nodef, w + o_prep, w + o_er1);
    k_e1<<<gE, 256, 0, stream>>>(src, dst, nodef, w + o_prep, w + o_er1, w + o_facc);
    k_n1<<<gN, 256, 0, stream>>>(w + o_facc, gat1_W, gat1_b, w + o_prep, w + o_el2, w + o_er2);
    k_e2<<<gE, 256, 0, stream>>>(src, dst, w + o_el2, w + o_er2, w + o_w2, w + o_den2);
    k_e3<<<gE, 256, 0, stream>>>(src, dst, w + o_w2, w + o_den2, w + o_q);
    k_r<<<dim3(64, 2), 256, 0, stream>>>(w + o_facc, gat1_W, gat1_b, w + o_q, w + o_A);
    k_final<<<1, 128, 0, stream>>>(w + o_A, gat2_W, gat2_b, Wg1, bg1, w + o_h2, vocab,
                                   W2, W3, (float*)d_out, out_size);
}

// Round 3
// 694.875 us; speedup vs baseline: 1.6384x; 1.0010x over previous
//
#include <hip/hip_runtime.h>
#include <math.h>

#define NN 50000
#define NE 800000

__device__ __forceinline__ float lrelu(float x, float s) { return x >= 0.f ? x : s * x; }

// prep[0..79]=u (W2h0@al2), prep[80..159]=v (W2h0@ar2), prep[160..162]=wl1, prep[163..165]=wr1
__global__ void k_prep(const float* __restrict__ W1, const float* __restrict__ al1,
                       const float* __restrict__ ar1, const float* __restrict__ W2,
                       const float* __restrict__ al2, const float* __restrict__ ar2,
                       float* __restrict__ prep) {
    int t = threadIdx.x;  // 128
    if (t < 80) {
        float u = 0.f, v = 0.f;
        for (int j = 0; j < 30; ++j) {
            float w = W2[t * 60 + j];  // head0 cols of [80, 60]
            u += w * al2[j];           // al2 row 0 of [2,30]
            v += w * ar2[j];
        }
        prep[t] = u;
        prep[80 + t] = v;
    } else if (t < 83) {
        int c = t - 80;
        float a = 0.f, b = 0.f;
        for (int f = 0; f < 80; ++f) {
            float w = W1[c * 160 + f];  // head0 cols of [3, 160]
            a += w * al1[f];            // al1 row 0 of [2,80]
            b += w * ar1[f];
        }
        prep[160 + c] = a;
        prep[163 + c] = b;
    }
}

// er1[g][n] = feat[g][n] . wr1
__global__ void k_er1(const float* __restrict__ nodef, const float* __restrict__ prep,
                      float* __restrict__ er1) {
    int g = blockIdx.y;
    int n = blockIdx.x * blockDim.x + threadIdx.x;
    if (n >= NN) return;
    const float* f = nodef + ((size_t)g * NN + n) * 3;
    er1[g * NN + n] = f[0] * prep[163] + f[1] * prep[164] + f[2] * prep[165];
}

// 4*NE threads; thread handles component c=idx&3 of edge e=idx>>2.
// w1 = exp(lrelu(feat[s].wl1 + er1[d])); f{x,y,z}[d] += w1*feat[s][c]; fw[d] += w1
__global__ void k_e1(const int* __restrict__ src, const int* __restrict__ dst,
                     const float* __restrict__ nodef, const float* __restrict__ prep,
                     const float* __restrict__ er1,
                     float* __restrict__ fx, float* __restrict__ fy,
                     float* __restrict__ fz, float* __restrict__ fw) {
    int g = blockIdx.y;
    unsigned int idx = blockIdx.x * blockDim.x + threadIdx.x;
    if (idx >= 4u * NE) return;
    unsigned int e = idx >> 2;
    int c = idx & 3;
    int s = src[(size_t)g * NE + e], d = dst[(size_t)g * NE + e];
    const float* f = nodef + ((size_t)g * NN + s) * 3;
    float f0 = f[0], f1 = f[1], f2 = f[2];
    float el = f0 * prep[160] + f1 * prep[161] + f2 * prep[162];
    float wv = __expf(lrelu(el + er1[g * NN + d], 0.2f));
    float val = (c == 0) ? wv * f0 : (c == 1) ? wv * f1 : (c == 2) ? wv * f2 : wv;
    float* tgt = (c == 0) ? fx : (c == 1) ? fy : (c == 2) ? fz : fw;
    atomicAdd(&tgt[g * NN + d], val);
}

// Per node: g1 = relu((fx,fy,fz)/fw @ W1h0 + b1); el2 = g1.u, er2 = g1.v
__global__ void k_n1(const float* __restrict__ fx, const float* __restrict__ fy,
                     const float* __restrict__ fz, const float* __restrict__ fw,
                     const float* __restrict__ W1, const float* __restrict__ b1,
                     const float* __restrict__ prep,
                     float* __restrict__ el2, float* __restrict__ er2) {
    __shared__ float sW[240], sB[80], sU[80], sV[80];
    for (int t = threadIdx.x; t < 80; t += blockDim.x) {
        sW[t] = W1[t];
        sW[80 + t] = W1[160 + t];
        sW[160 + t] = W1[320 + t];
        sB[t] = b1[t];
        sU[t] = prep[t];
        sV[t] = prep[80 + t];
    }
    __syncthreads();
    int g = blockIdx.y;
    int n = blockIdx.x * blockDim.x + threadIdx.x;
    if (n >= NN) return;
    float wsum = fw[g * NN + n];
    float inv = wsum != 0.f ? 1.f / wsum : 0.f;
    float c0 = fx[g * NN + n] * inv, c1 = fy[g * NN + n] * inv, c2 = fz[g * NN + n] * inv;
    float el = 0.f, er = 0.f;
    #pragma unroll
    for (int f = 0; f < 80; ++f) {
        float gg = c0 * sW[f] + c1 * sW[80 + f] + c2 * sW[160 + f] + sB[f];
        gg = gg > 0.f ? gg : 0.f;
        el += gg * sU[f];
        er += gg * sV[f];
    }
    el2[g * NN + n] = el;
    er2[g * NN + n] = er;
}

// Per edge: w2 = exp(lrelu(el2[s]+er2[d])); den2[d] += w2; store w2
__global__ void k_e2(const int* __restrict__ src, const int* __restrict__ dst,
                     const float* __restrict__ el2, const float* __restrict__ er2,
                     float* __restrict__ w2, float* __restrict__ den2) {
    int g = blockIdx.y;
    int e = blockIdx.x * blockDim.x + threadIdx.x;
    if (e >= NE) return;
    int s = src[(size_t)g * NE + e], d = dst[(size_t)g * NE + e];
    float wv = __expf(lrelu(el2[g * NN + s] + er2[g * NN + d], 0.2f));
    w2[(size_t)g * NE + e] = wv;
    atomicAdd(&den2[g * NN + d], wv);
}

// Per edge: q[s] += w2 / den2[d]
__global__ void k_e3(const int* __restrict__ src, const int* __restrict__ dst,
                     const float* __restrict__ w2, const float* __restrict__ den2,
                     float* __restrict__ q) {
    int g = blockIdx.y;
    int e = blockIdx.x * blockDim.x + threadIdx.x;
    if (e >= NE) return;
    int s = src[(size_t)g * NE + e], d = dst[(size_t)g * NE + e];
    atomicAdd(&q[g * NN + s], w2[(size_t)g * NE + e] / den2[g * NN + d]);
}

// A[g][0..79] = sum_n q[n] * g1[n]
__global__ void k_r(const float* __restrict__ fx, const float* __restrict__ fy,
                    const float* __restrict__ fz, const float* __restrict__ fw,
                    const float* __restrict__ W1, const float* __restrict__ b1,
                    const float* __restrict__ q, float* __restrict__ A) {
    __shared__ float sW[240], sB[80], sA[80];
    for (int t = threadIdx.x; t < 80; t += blockDim.x) {
        sW[t] = W1[t];
        sW[80 + t] = W1[160 + t];
        sW[160 + t] = W1[320 + t];
        sB[t] = b1[t];
        sA[t] = 0.f;
    }
    __syncthreads();
    int g = blockIdx.y;
    int base = threadIdx.x % 80;
    for (int n = blockIdx.x * blockDim.x + threadIdx.x; n < NN; n += gridDim.x * blockDim.x) {
        float qn = q[g * NN + n];
        if (qn == 0.f) continue;
        float wsum = fw[g * NN + n];
        float inv = wsum != 0.f ? 1.f / wsum : 0.f;
        float c0 = fx[g * NN + n] * inv, c1 = fy[g * NN + n] * inv, c2 = fz[g * NN + n] * inv;
        for (int k = 0; k < 80; ++k) {
            int f = base + k;
            f = f >= 80 ? f - 80 : f;
            float gg = c0 * sW[f] + c1 * sW[80 + f] + c2 * sW[160 + f] + sB[f];
            gg = gg > 0.f ? gg : 0.f;
            atomicAdd(&sA[f], qn * gg);
        }
    }
    __syncthreads();
    for (int t = threadIdx.x; t < 80; t += blockDim.x) atomicAdd(&A[g * 80 + t], sA[t]);
}

// Image branch: emb = x@W_lin1 [2,30]; h = lrelu(Wc1@emb); h2 = lrelu(Wc2@h) [30]
__global__ void k_img(const float* __restrict__ x, const float* __restrict__ W1,
                      const float* __restrict__ Wc1, const float* __restrict__ Wc2,
                      float* __restrict__ h2out) {
    __shared__ float part[240];
    __shared__ float emb[60];
    __shared__ float hh[80 * 30];
    int t = threadIdx.x;  // 256 threads
    if (t < 240) {
        int g = t / 120, k = (t / 4) % 30, q = t % 4;
        float acc = 0.f;
        const float* xp = x + g * 4096 + q * 1024;
        for (int c = 0; c < 1024; ++c) acc += xp[c] * W1[(q * 1024 + c) * 30 + k];
        part[t] = acc;
    }
    __syncthreads();
    if (t < 60) {
        int g = t / 30, k = t % 30;
        int b = g * 120 + k * 4;
        emb[t] = part[b] + part[b + 1] + part[b + 2] + part[b + 3];
    }
    __syncthreads();
    for (int p = t; p < 2400; p += 256) {
        int i = p / 30, j = p % 30;
        float v = Wc1[i * 2 + 0] * emb[j] + Wc1[i * 2 + 1] * emb[30 + j];
        hh[p] = lrelu(v, 0.01f);
    }
    __syncthreads();
    if (t < 30) {
        float acc = 0.f;
        for (int i = 0; i < 80; ++i) acc += Wc2[i] * hh[i * 30 + t];
        h2out[t] = lrelu(acc, 0.01f);
    }
}

// Final head: a_i = A_i @ W2h0 / N + b2; gr; hc; two tiny matmuls; log_softmax
__global__ void k_final(const float* __restrict__ A, const float* __restrict__ W2g,
                        const float* __restrict__ b2, const float* __restrict__ Wg1,
                        const float* __restrict__ bg1, const float* __restrict__ h2,
                        const float* __restrict__ vocab, const float* __restrict__ W2f,
                        const float* __restrict__ W3, float* __restrict__ out, int out_size) {
    __shared__ float a[60];
    __shared__ float hc[70];
    __shared__ float tt[80];
    __shared__ float lp[2];
    int t = threadIdx.x;  // 128
    if (t < 60) {
        int i = t / 30, j = t % 30;
        float acc = 0.f;
        for (int f = 0; f < 80; ++f) acc += A[i * 80 + f] * W2g[f * 60 + j];
        a[t] = acc * (1.f / NN) + b2[j];
    }
    __syncthreads();
    if (t < 30) {
        float acc = bg1[t];
        for (int j = 0; j < 60; ++j) acc += a[j] * Wg1[j * 30 + t];
        hc[t] = acc;
        hc[30 + t] = h2[t];
        if (t < 10) hc[60 + t] = vocab[t];
    }
    __syncthreads();
    if (t < 80) {
        float acc = 0.f;
        for (int qd = 0; qd < 70; ++qd) acc += hc[qd] * W2f[qd * 80 + t];
        tt[t] = acc;
    }
    __syncthreads();
    if (t < 2) {
        float acc = 0.f;
        for (int p = 0; p < 80; ++p) acc += tt[p] * W3[p * 2 + t];
        lp[t] = acc;
    }
    __syncthreads();
    if (t == 0) {
        float m = fmaxf(lp[0], lp[1]);
        float lse = m + logf(expf(lp[0] - m) + expf(lp[1] - m));
        out[0] = lp[0] - lse;
        out[1] = lp[1] - lse;
    }
    for (int i = 2 + t; i < out_size; i += blockDim.x) out[i] = 0.f;
}

extern "C" void kernel_launch(void* const* d_in, const int* in_sizes, int n_in,
                              void* d_out, int out_size, void* d_ws, size_t ws_size,
                              hipStream_t stream) {
    const float* x        = (const float*)d_in[0];
    const float* vocab    = (const float*)d_in[1];
    const float* nodef    = (const float*)d_in[2];
    const int*   src      = (const int*)d_in[3];
    const int*   dst      = (const int*)d_in[4];
    const float* W_lin1   = (const float*)d_in[5];
    const float* Wc1      = (const float*)d_in[6];
    const float* Wc2      = (const float*)d_in[7];
    const float* gat1_W   = (const float*)d_in[8];
    const float* gat1_al  = (const float*)d_in[9];
    const float* gat1_ar  = (const float*)d_in[10];
    const float* gat1_b   = (const float*)d_in[11];
    const float* gat2_W   = (const float*)d_in[12];
    const float* gat2_al  = (const float*)d_in[13];
    const float* gat2_ar  = (const float*)d_in[14];
    const float* gat2_b   = (const float*)d_in[15];
    const float* Wg1      = (const float*)d_in[16];
    const float* bg1      = (const float*)d_in[17];
    const float* W2       = (const float*)d_in[18];
    const float* W3       = (const float*)d_in[19];
    (void)in_sizes; (void)n_in; (void)ws_size;

    float* w = (float*)d_ws;
    size_t off = 0;
    auto alloc = [&](size_t n) { size_t o = off; off += (n + 63) & ~(size_t)63; return o; };
    size_t o_h2   = alloc(32);
    size_t o_prep = alloc(192);
    size_t o_er1  = alloc(2 * NN);
    size_t o_el2  = alloc(2 * NN);
    size_t o_er2  = alloc(2 * NN);
    size_t o_w2   = alloc((size_t)2 * NE);
    size_t o_fx   = alloc(2 * NN);  // zero-region start
    size_t o_fy   = alloc(2 * NN);
    size_t o_fz   = alloc(2 * NN);
    size_t o_fw   = alloc(2 * NN);
    size_t o_den2 = alloc(2 * NN);
    size_t o_q    = alloc(2 * NN);
    size_t o_A    = alloc(192);
    size_t o_zend = off;

    hipMemsetAsync(w + o_fx, 0, (o_zend - o_fx) * sizeof(float), stream);
    k_prep<<<1, 128, 0, stream>>>(gat1_W, gat1_al, gat1_ar, gat2_W, gat2_al, gat2_ar, w + o_prep);
    k_img<<<1, 256, 0, stream>>>(x, W_lin1, Wc1, Wc2, w + o_h2);

    dim3 gN((NN + 255) / 256, 2);
    dim3 gE((NE + 255) / 256, 2);
    dim3 gE4((4 * NE + 255) / 256, 2);
    k_er1<<<gN, 256, 0, stream>>>(nodef, w + o_prep, w + o_er1);
    k_e1<<<gE4, 256, 0, stream>>>(src, dst, nodef, w + o_prep, w + o_er1,
                                  w + o_fx, w + o_fy, w + o_fz, w + o_fw);
    k_n1<<<gN, 256, 0, stream>>>(w + o_fx, w + o_fy, w + o_fz, w + o_fw,
                                 gat1_W, gat1_b, w + o_prep, w + o_el2, w + o_er2);
    k_e2<<<gE, 256, 0, stream>>>(src, dst, w + o_el2, w + o_er2, w + o_w2, w + o_den2);
    k_e3<<<gE, 256, 0, stream>>>(src, dst, w + o_w2, w + o_den2, w + o_q);
    k_r<<<dim3(64, 2), 256, 0, stream>>>(w + o_fx, w + o_fy, w + o_fz, w + o_fw,
                                         gat1_W, gat1_b, w + o_q, w + o_A);
    k_final<<<1, 128, 0, stream>>>(w + o_A, gat2_W, gat2_b, Wg1, bg1, w + o_h2, vocab,
                                   W2, W3, (float*)d_out, out_size);
}

// Round 4
// 456.247 us; speedup vs baseline: 2.4954x; 1.5230x over previous
//
#include <hip/hip_runtime.h>
#include <math.h>

#define NN 50000
#define NE 800000

__device__ __forceinline__ float lrelu(float x, float s) { return x >= 0.f ? x : s * x; }

// prep[0..79]=u (W2h0@al2), prep[80..159]=v (W2h0@ar2), prep[160..162]=wl1, prep[163..165]=wr1
__global__ void k_prep(const float* __restrict__ W1, const float* __restrict__ al1,
                       const float* __restrict__ ar1, const float* __restrict__ W2,
                       const float* __restrict__ al2, const float* __restrict__ ar2,
                       float* __restrict__ prep) {
    int t = threadIdx.x;  // 128
    if (t < 80) {
        float u = 0.f, v = 0.f;
        for (int j = 0; j < 30; ++j) {
            float w = W2[t * 60 + j];  // head0 cols of [80, 60]
            u += w * al2[j];           // al2 row 0 of [2,30]
            v += w * ar2[j];
        }
        prep[t] = u;
        prep[80 + t] = v;
    } else if (t < 83) {
        int c = t - 80;
        float a = 0.f, b = 0.f;
        for (int f = 0; f < 80; ++f) {
            float w = W1[c * 160 + f];  // head0 cols of [3, 160]
            a += w * al1[f];            // al1 row 0 of [2,80]
            b += w * ar1[f];
        }
        prep[160 + c] = a;
        prep[163 + c] = b;
    }
}

// er1[g][n] = feat[g][n] . wr1
__global__ void k_er1(const float* __restrict__ nodef, const float* __restrict__ prep,
                      float* __restrict__ er1) {
    int g = blockIdx.y;
    int n = blockIdx.x * blockDim.x + threadIdx.x;
    if (n >= NN) return;
    const float* f = nodef + ((size_t)g * NN + n) * 3;
    er1[g * NN + n] = f[0] * prep[163] + f[1] * prep[164] + f[2] * prep[165];
}

// 4*NE threads; lanes 4e..4e+3 handle edge e, component c=idx&3.
// w1 = exp(lrelu(feat[s].wl1 + er1[d])); facc4[(g*NN+d)*4+c] += {w1*f0,w1*f1,w1*f2,w1}[c]
// Adjacent lanes hit 16 contiguous bytes of ONE 64B line -> TCC merges into one line-op.
__global__ void k_e1(const int* __restrict__ src, const int* __restrict__ dst,
                     const float* __restrict__ nodef, const float* __restrict__ prep,
                     const float* __restrict__ er1, float* __restrict__ facc4) {
    int g = blockIdx.y;
    unsigned int idx = blockIdx.x * blockDim.x + threadIdx.x;
    if (idx >= 4u * NE) return;
    unsigned int e = idx >> 2;
    int c = idx & 3;
    int s = src[(size_t)g * NE + e], d = dst[(size_t)g * NE + e];
    const float* f = nodef + ((size_t)g * NN + s) * 3;
    float f0 = f[0], f1 = f[1], f2 = f[2];
    float el = f0 * prep[160] + f1 * prep[161] + f2 * prep[162];
    float wv = __expf(lrelu(el + er1[g * NN + d], 0.2f));
    float val = (c == 0) ? wv * f0 : (c == 1) ? wv * f1 : (c == 2) ? wv * f2 : wv;
    atomicAdd(&facc4[((size_t)g * NN + d) * 4 + c], val);
}

// Per node: g1 = relu(facc.xyz/facc.w @ W1h0 + b1); el2 = g1.u, er2 = g1.v
__global__ void k_n1(const float* __restrict__ facc4, const float* __restrict__ W1,
                     const float* __restrict__ b1, const float* __restrict__ prep,
                     float* __restrict__ el2, float* __restrict__ er2) {
    __shared__ float sW[240], sB[80], sU[80], sV[80];
    for (int t = threadIdx.x; t < 80; t += blockDim.x) {
        sW[t] = W1[t];
        sW[80 + t] = W1[160 + t];
        sW[160 + t] = W1[320 + t];
        sB[t] = b1[t];
        sU[t] = prep[t];
        sV[t] = prep[80 + t];
    }
    __syncthreads();
    int g = blockIdx.y;
    int n = blockIdx.x * blockDim.x + threadIdx.x;
    if (n >= NN) return;
    float4 fa = *(const float4*)(facc4 + ((size_t)g * NN + n) * 4);
    float inv = fa.w != 0.f ? 1.f / fa.w : 0.f;
    float c0 = fa.x * inv, c1 = fa.y * inv, c2 = fa.z * inv;
    float el = 0.f, er = 0.f;
    #pragma unroll
    for (int f = 0; f < 80; ++f) {
        float gg = c0 * sW[f] + c1 * sW[80 + f] + c2 * sW[160 + f] + sB[f];
        gg = gg > 0.f ? gg : 0.f;
        el += gg * sU[f];
        er += gg * sV[f];
    }
    el2[g * NN + n] = el;
    er2[g * NN + n] = er;
}

// Per edge: den2[d] += exp(lrelu(el2[s]+er2[d]))
__global__ void k_e2(const int* __restrict__ src, const int* __restrict__ dst,
                     const float* __restrict__ el2, const float* __restrict__ er2,
                     float* __restrict__ den2) {
    int g = blockIdx.y;
    int e = blockIdx.x * blockDim.x + threadIdx.x;
    if (e >= NE) return;
    int s = src[(size_t)g * NE + e], d = dst[(size_t)g * NE + e];
    float wv = __expf(lrelu(el2[g * NN + s] + er2[g * NN + d], 0.2f));
    atomicAdd(&den2[g * NN + d], wv);
}

// Per edge: q[s] += exp(lrelu(el2[s]+er2[d])) / den2[d]
__global__ void k_e3(const int* __restrict__ src, const int* __restrict__ dst,
                     const float* __restrict__ el2, const float* __restrict__ er2,
                     const float* __restrict__ den2, float* __restrict__ q) {
    int g = blockIdx.y;
    int e = blockIdx.x * blockDim.x + threadIdx.x;
    if (e >= NE) return;
    int s = src[(size_t)g * NE + e], d = dst[(size_t)g * NE + e];
    float wv = __expf(lrelu(el2[g * NN + s] + er2[g * NN + d], 0.2f));
    atomicAdd(&q[g * NN + s], wv / den2[g * NN + d]);
}

// A[g][0..79] = sum_n q[n] * g1[n]
__global__ void k_r(const float* __restrict__ facc4, const float* __restrict__ W1,
                    const float* __restrict__ b1, const float* __restrict__ q,
                    float* __restrict__ A) {
    __shared__ float sW[240], sB[80], sA[80];
    for (int t = threadIdx.x; t < 80; t += blockDim.x) {
        sW[t] = W1[t];
        sW[80 + t] = W1[160 + t];
        sW[160 + t] = W1[320 + t];
        sB[t] = b1[t];
        sA[t] = 0.f;
    }
    __syncthreads();
    int g = blockIdx.y;
    int base = threadIdx.x % 80;
    for (int n = blockIdx.x * blockDim.x + threadIdx.x; n < NN; n += gridDim.x * blockDim.x) {
        float qn = q[g * NN + n];
        if (qn == 0.f) continue;
        float4 fa = *(const float4*)(facc4 + ((size_t)g * NN + n) * 4);
        float inv = fa.w != 0.f ? 1.f / fa.w : 0.f;
        float c0 = fa.x * inv, c1 = fa.y * inv, c2 = fa.z * inv;
        for (int k = 0; k < 80; ++k) {
            int f = base + k;
            f = f >= 80 ? f - 80 : f;
            float gg = c0 * sW[f] + c1 * sW[80 + f] + c2 * sW[160 + f] + sB[f];
            gg = gg > 0.f ? gg : 0.f;
            atomicAdd(&sA[f], qn * gg);
        }
    }
    __syncthreads();
    for (int t = threadIdx.x; t < 80; t += blockDim.x) atomicAdd(&A[g * 80 + t], sA[t]);
}

// Image branch: emb = x@W_lin1 [2,30]; h = lrelu(Wc1@emb); h2 = lrelu(Wc2@h) [30]
__global__ void k_img(const float* __restrict__ x, const float* __restrict__ W1,
                      const float* __restrict__ Wc1, const float* __restrict__ Wc2,
                      float* __restrict__ h2out) {
    __shared__ float part[240];
    __shared__ float emb[60];
    __shared__ float hh[80 * 30];
    int t = threadIdx.x;  // 256 threads
    if (t < 240) {
        int g = t / 120, k = (t / 4) % 30, q = t % 4;
        float acc = 0.f;
        const float* xp = x + g * 4096 + q * 1024;
        for (int c = 0; c < 1024; ++c) acc += xp[c] * W1[(q * 1024 + c) * 30 + k];
        part[t] = acc;
    }
    __syncthreads();
    if (t < 60) {
        int g = t / 30, k = t % 30;
        int b = g * 120 + k * 4;
        emb[t] = part[b] + part[b + 1] + part[b + 2] + part[b + 3];
    }
    __syncthreads();
    for (int p = t; p < 2400; p += 256) {
        int i = p / 30, j = p % 30;
        float v = Wc1[i * 2 + 0] * emb[j] + Wc1[i * 2 + 1] * emb[30 + j];
        hh[p] = lrelu(v, 0.01f);
    }
    __syncthreads();
    if (t < 30) {
        float acc = 0.f;
        for (int i = 0; i < 80; ++i) acc += Wc2[i] * hh[i * 30 + t];
        h2out[t] = lrelu(acc, 0.01f);
    }
}

// Final head: a_i = A_i @ W2h0 / N + b2; gr; hc; two tiny matmuls; log_softmax
__global__ void k_final(const float* __restrict__ A, const float* __restrict__ W2g,
                        const float* __restrict__ b2, const float* __restrict__ Wg1,
                        const float* __restrict__ bg1, const float* __restrict__ h2,
                        const float* __restrict__ vocab, const float* __restrict__ W2f,
                        const float* __restrict__ W3, float* __restrict__ out, int out_size) {
    __shared__ float a[60];
    __shared__ float hc[70];
    __shared__ float tt[80];
    __shared__ float lp[2];
    int t = threadIdx.x;  // 128
    if (t < 60) {
        int i = t / 30, j = t % 30;
        float acc = 0.f;
        for (int f = 0; f < 80; ++f) acc += A[i * 80 + f] * W2g[f * 60 + j];
        a[t] = acc * (1.f / NN) + b2[j];
    }
    __syncthreads();
    if (t < 30) {
        float acc = bg1[t];
        for (int j = 0; j < 60; ++j) acc += a[j] * Wg1[j * 30 + t];
        hc[t] = acc;
        hc[30 + t] = h2[t];
        if (t < 10) hc[60 + t] = vocab[t];
    }
    __syncthreads();
    if (t < 80) {
        float acc = 0.f;
        for (int qd = 0; qd < 70; ++qd) acc += hc[qd] * W2f[qd * 80 + t];
        tt[t] = acc;
    }
    __syncthreads();
    if (t < 2) {
        float acc = 0.f;
        for (int p = 0; p < 80; ++p) acc += tt[p] * W3[p * 2 + t];
        lp[t] = acc;
    }
    __syncthreads();
    if (t == 0) {
        float m = fmaxf(lp[0], lp[1]);
        float lse = m + logf(expf(lp[0] - m) + expf(lp[1] - m));
        out[0] = lp[0] - lse;
        out[1] = lp[1] - lse;
    }
    for (int i = 2 + t; i < out_size; i += blockDim.x) out[i] = 0.f;
}

extern "C" void kernel_launch(void* const* d_in, const int* in_sizes, int n_in,
                              void* d_out, int out_size, void* d_ws, size_t ws_size,
                              hipStream_t stream) {
    const float* x        = (const float*)d_in[0];
    const float* vocab    = (const float*)d_in[1];
    const float* nodef    = (const float*)d_in[2];
    const int*   src      = (const int*)d_in[3];
    const int*   dst      = (const int*)d_in[4];
    const float* W_lin1   = (const float*)d_in[5];
    const float* Wc1      = (const float*)d_in[6];
    const float* Wc2      = (const float*)d_in[7];
    const float* gat1_W   = (const float*)d_in[8];
    const float* gat1_al  = (const float*)d_in[9];
    const float* gat1_ar  = (const float*)d_in[10];
    const float* gat1_b   = (const float*)d_in[11];
    const float* gat2_W   = (const float*)d_in[12];
    const float* gat2_al  = (const float*)d_in[13];
    const float* gat2_ar  = (const float*)d_in[14];
    const float* gat2_b   = (const float*)d_in[15];
    const float* Wg1      = (const float*)d_in[16];
    const float* bg1      = (const float*)d_in[17];
    const float* W2       = (const float*)d_in[18];
    const float* W3       = (const float*)d_in[19];
    (void)in_sizes; (void)n_in; (void)ws_size;

    float* w = (float*)d_ws;
    size_t off = 0;
    auto alloc = [&](size_t n) { size_t o = off; off += (n + 63) & ~(size_t)63; return o; };
    size_t o_h2   = alloc(32);
    size_t o_prep = alloc(192);
    size_t o_er1  = alloc(2 * NN);
    size_t o_el2  = alloc(2 * NN);
    size_t o_er2  = alloc(2 * NN);
    size_t o_facc = alloc((size_t)2 * NN * 4);  // zero-region start
    size_t o_den2 = alloc(2 * NN);
    size_t o_q    = alloc(2 * NN);
    size_t o_A    = alloc(192);
    size_t o_zend = off;

    hipMemsetAsync(w + o_facc, 0, (o_zend - o_facc) * sizeof(float), stream);
    k_prep<<<1, 128, 0, stream>>>(gat1_W, gat1_al, gat1_ar, gat2_W, gat2_al, gat2_ar, w + o_prep);
    k_img<<<1, 256, 0, stream>>>(x, W_lin1, Wc1, Wc2, w + o_h2);

    dim3 gN((NN + 255) / 256, 2);
    dim3 gE((NE + 255) / 256, 2);
    dim3 gE4((4 * NE + 255) / 256, 2);
    k_er1<<<gN, 256, 0, stream>>>(nodef, w + o_prep, w + o_er1);
    k_e1<<<gE4, 256, 0, stream>>>(src, dst, nodef, w + o_prep, w + o_er1, w + o_facc);
    k_n1<<<gN, 256, 0, stream>>>(w + o_facc, gat1_W, gat1_b, w + o_prep, w + o_el2, w + o_er2);
    k_e2<<<gE, 256, 0, stream>>>(src, dst, w + o_el2, w + o_er2, w + o_den2);
    k_e3<<<gE, 256, 0, stream>>>(src, dst, w + o_el2, w + o_er2, w + o_den2, w + o_q);
    k_r<<<dim3(64, 2), 256, 0, stream>>>(w + o_facc, gat1_W, gat1_b, w + o_q, w + o_A);
    k_final<<<1, 128, 0, stream>>>(w + o_A, gat2_W, gat2_b, Wg1, bg1, w + o_h2, vocab,
                                   W2, W3, (float*)d_out, out_size);
}

// Round 5
// 378.497 us; speedup vs baseline: 3.0080x; 1.2054x over previous
//
#include <hip/hip_runtime.h>
#include <math.h>

#define NN 50000
#define NE 800000
#define RT 128  // k_r node tile

__device__ __forceinline__ float lrelu(float x, float s) { return x >= 0.f ? x : s * x; }

// prep[0..79]=u (W2h0@al2), prep[80..159]=v (W2h0@ar2), prep[160..162]=wl1, prep[163..165]=wr1
__global__ void k_prep(const float* __restrict__ W1, const float* __restrict__ al1,
                       const float* __restrict__ ar1, const float* __restrict__ W2,
                       const float* __restrict__ al2, const float* __restrict__ ar2,
                       float* __restrict__ prep) {
    int t = threadIdx.x;  // 128
    if (t < 80) {
        float u = 0.f, v = 0.f;
        for (int j = 0; j < 30; ++j) {
            float w = W2[t * 60 + j];  // head0 cols of [80, 60]
            u += w * al2[j];           // al2 row 0 of [2,30]
            v += w * ar2[j];
        }
        prep[t] = u;
        prep[80 + t] = v;
    } else if (t < 83) {
        int c = t - 80;
        float a = 0.f, b = 0.f;
        for (int f = 0; f < 80; ++f) {
            float w = W1[c * 160 + f];  // head0 cols of [3, 160]
            a += w * al1[f];            // al1 row 0 of [2,80]
            b += w * ar1[f];
        }
        prep[160 + c] = a;
        prep[163 + c] = b;
    }
}

// er1[g][n] = feat[g][n] . wr1
__global__ void k_er1(const float* __restrict__ nodef, const float* __restrict__ prep,
                      float* __restrict__ er1) {
    int g = blockIdx.y;
    int n = blockIdx.x * blockDim.x + threadIdx.x;
    if (n >= NN) return;
    const float* f = nodef + ((size_t)g * NN + n) * 3;
    er1[g * NN + n] = f[0] * prep[163] + f[1] * prep[164] + f[2] * prep[165];
}

// 4*NE threads; lanes 4e..4e+3 handle edge e, component c=idx&3.
// w1 = exp(lrelu(feat[s].wl1 + er1[d])); facc4[(g*NN+d)*4+c] += {w1*f0,w1*f1,w1*f2,w1}[c]
// Adjacent lanes hit 16 contiguous bytes of ONE 64B line -> TCC merges the quad.
__global__ void k_e1(const int* __restrict__ src, const int* __restrict__ dst,
                     const float* __restrict__ nodef, const float* __restrict__ prep,
                     const float* __restrict__ er1, float* __restrict__ facc4) {
    int g = blockIdx.y;
    unsigned int idx = blockIdx.x * blockDim.x + threadIdx.x;
    if (idx >= 4u * NE) return;
    unsigned int e = idx >> 2;
    int c = idx & 3;
    int s = src[(size_t)g * NE + e], d = dst[(size_t)g * NE + e];
    const float* f = nodef + ((size_t)g * NN + s) * 3;
    float f0 = f[0], f1 = f[1], f2 = f[2];
    float el = f0 * prep[160] + f1 * prep[161] + f2 * prep[162];
    float wv = __expf(lrelu(el + er1[g * NN + d], 0.2f));
    float val = (c == 0) ? wv * f0 : (c == 1) ? wv * f1 : (c == 2) ? wv * f2 : wv;
    atomicAdd(&facc4[((size_t)g * NN + d) * 4 + c], val);
}

// Per node: g1 = relu(facc.xyz/facc.w @ W1h0 + b1); el2 = g1.u, er2 = g1.v
__global__ void k_n1(const float* __restrict__ facc4, const float* __restrict__ W1,
                     const float* __restrict__ b1, const float* __restrict__ prep,
                     float* __restrict__ el2, float* __restrict__ er2) {
    __shared__ float sW[240], sB[80], sU[80], sV[80];
    for (int t = threadIdx.x; t < 80; t += blockDim.x) {
        sW[t] = W1[t];
        sW[80 + t] = W1[160 + t];
        sW[160 + t] = W1[320 + t];
        sB[t] = b1[t];
        sU[t] = prep[t];
        sV[t] = prep[80 + t];
    }
    __syncthreads();
    int g = blockIdx.y;
    int n = blockIdx.x * blockDim.x + threadIdx.x;
    if (n >= NN) return;
    float4 fa = *(const float4*)(facc4 + ((size_t)g * NN + n) * 4);
    float inv = fa.w != 0.f ? 1.f / fa.w : 0.f;
    float c0 = fa.x * inv, c1 = fa.y * inv, c2 = fa.z * inv;
    float el = 0.f, er = 0.f;
    #pragma unroll
    for (int f = 0; f < 80; ++f) {
        float gg = c0 * sW[f] + c1 * sW[80 + f] + c2 * sW[160 + f] + sB[f];
        gg = gg > 0.f ? gg : 0.f;
        el += gg * sU[f];
        er += gg * sV[f];
    }
    el2[g * NN + n] = el;
    er2[g * NN + n] = er;
}

// Per edge: den2[d] += exp(lrelu(el2[s]+er2[d]))
__global__ void k_e2(const int* __restrict__ src, const int* __restrict__ dst,
                     const float* __restrict__ el2, const float* __restrict__ er2,
                     float* __restrict__ den2) {
    int g = blockIdx.y;
    int e = blockIdx.x * blockDim.x + threadIdx.x;
    if (e >= NE) return;
    int s = src[(size_t)g * NE + e], d = dst[(size_t)g * NE + e];
    float wv = __expf(lrelu(el2[g * NN + s] + er2[g * NN + d], 0.2f));
    atomicAdd(&den2[g * NN + d], wv);
}

// Per edge: q[s] += exp(lrelu(el2[s]+er2[d])) / den2[d]
__global__ void k_e3(const int* __restrict__ src, const int* __restrict__ dst,
                     const float* __restrict__ el2, const float* __restrict__ er2,
                     const float* __restrict__ den2, float* __restrict__ q) {
    int g = blockIdx.y;
    int e = blockIdx.x * blockDim.x + threadIdx.x;
    if (e >= NE) return;
    int s = src[(size_t)g * NE + e], d = dst[(size_t)g * NE + e];
    float wv = __expf(lrelu(el2[g * NN + s] + er2[g * NN + d], 0.2f));
    atomicAdd(&q[g * NN + s], wv / den2[g * NN + d]);
}

// A[g][0..79] = sum_n q[n] * g1[n]  — register accumulation, no hot-loop atomics.
// 256 threads = 3 groups x 80 features; 128-node LDS tiles.
__global__ void k_r(const float* __restrict__ facc4, const float* __restrict__ W1,
                    const float* __restrict__ b1, const float* __restrict__ q,
                    float* __restrict__ A) {
    __shared__ float4 sF[RT];
    __shared__ float sQ[RT];
    __shared__ float sW[240], sB[80];
    __shared__ float sA[240];
    int t = threadIdx.x;
    for (int i = t; i < 80; i += 256) {
        sW[i] = W1[i];
        sW[80 + i] = W1[160 + i];
        sW[160 + i] = W1[320 + i];
        sB[i] = b1[i];
    }
    int g = blockIdx.y;
    int grp = t / 80, f = t - grp * 80;  // grp 0..2 active (t<240)
    float acc = 0.f;
    for (int n0 = blockIdx.x * RT; n0 < NN; n0 += gridDim.x * RT) {
        __syncthreads();
        if (t < RT) {
            int n = n0 + t;
            sF[t] = (n < NN) ? *(const float4*)(facc4 + ((size_t)g * NN + n) * 4)
                             : make_float4(0.f, 0.f, 0.f, 0.f);
        } else if (t < 2 * RT) {
            int n = n0 + t - RT;
            sQ[t - RT] = (n < NN) ? q[g * NN + n] : 0.f;
        }
        __syncthreads();
        if (grp < 3) {
            for (int i = grp; i < RT; i += 3) {
                float qn = sQ[i];
                if (qn == 0.f) continue;
                float4 fa = sF[i];
                float inv = fa.w != 0.f ? 1.f / fa.w : 0.f;
                float c0 = fa.x * inv, c1 = fa.y * inv, c2 = fa.z * inv;
                float gg = c0 * sW[f] + c1 * sW[80 + f] + c2 * sW[160 + f] + sB[f];
                gg = gg > 0.f ? gg : 0.f;
                acc += qn * gg;
            }
        }
    }
    if (grp < 3) sA[t] = acc;
    __syncthreads();
    if (t < 80) atomicAdd(&A[g * 80 + t], sA[t] + sA[80 + t] + sA[160 + t]);
}

// Image branch: emb = x@W_lin1 [2,30]; h = lrelu(Wc1@emb); h2 = lrelu(Wc2@h) [30]
__global__ void k_img(const float* __restrict__ x, const float* __restrict__ W1,
                      const float* __restrict__ Wc1, const float* __restrict__ Wc2,
                      float* __restrict__ h2out) {
    __shared__ float part[240];
    __shared__ float emb[60];
    __shared__ float hh[80 * 30];
    int t = threadIdx.x;  // 256 threads
    if (t < 240) {
        int g = t / 120, k = (t / 4) % 30, q = t % 4;
        float acc = 0.f;
        const float* xp = x + g * 4096 + q * 1024;
        for (int c = 0; c < 1024; ++c) acc += xp[c] * W1[(q * 1024 + c) * 30 + k];
        part[t] = acc;
    }
    __syncthreads();
    if (t < 60) {
        int g = t / 30, k = t % 30;
        int b = g * 120 + k * 4;
        emb[t] = part[b] + part[b + 1] + part[b + 2] + part[b + 3];
    }
    __syncthreads();
    for (int p = t; p < 2400; p += 256) {
        int i = p / 30, j = p % 30;
        float v = Wc1[i * 2 + 0] * emb[j] + Wc1[i * 2 + 1] * emb[30 + j];
        hh[p] = lrelu(v, 0.01f);
    }
    __syncthreads();
    if (t < 30) {
        float acc = 0.f;
        for (int i = 0; i < 80; ++i) acc += Wc2[i] * hh[i * 30 + t];
        h2out[t] = lrelu(acc, 0.01f);
    }
}

// Final head: a_i = A_i @ W2h0 / N + b2; gr; hc; two tiny matmuls; log_softmax
__global__ void k_final(const float* __restrict__ A, const float* __restrict__ W2g,
                        const float* __restrict__ b2, const float* __restrict__ Wg1,
                        const float* __restrict__ bg1, const float* __restrict__ h2,
                        const float* __restrict__ vocab, const float* __restrict__ W2f,
                        const float* __restrict__ W3, float* __restrict__ out, int out_size) {
    __shared__ float a[60];
    __shared__ float hc[70];
    __shared__ float tt[80];
    __shared__ float lp[2];
    int t = threadIdx.x;  // 128
    if (t < 60) {
        int i = t / 30, j = t % 30;
        float acc = 0.f;
        for (int f = 0; f < 80; ++f) acc += A[i * 80 + f] * W2g[f * 60 + j];
        a[t] = acc * (1.f / NN) + b2[j];
    }
    __syncthreads();
    if (t < 30) {
        float acc = bg1[t];
        for (int j = 0; j < 60; ++j) acc += a[j] * Wg1[j * 30 + t];
        hc[t] = acc;
        hc[30 + t] = h2[t];
        if (t < 10) hc[60 + t] = vocab[t];
    }
    __syncthreads();
    if (t < 80) {
        float acc = 0.f;
        for (int qd = 0; qd < 70; ++qd) acc += hc[qd] * W2f[qd * 80 + t];
        tt[t] = acc;
    }
    __syncthreads();
    if (t < 2) {
        float acc = 0.f;
        for (int p = 0; p < 80; ++p) acc += tt[p] * W3[p * 2 + t];
        lp[t] = acc;
    }
    __syncthreads();
    if (t == 0) {
        float m = fmaxf(lp[0], lp[1]);
        float lse = m + logf(expf(lp[0] - m) + expf(lp[1] - m));
        out[0] = lp[0] - lse;
        out[1] = lp[1] - lse;
    }
    for (int i = 2 + t; i < out_size; i += blockDim.x) out[i] = 0.f;
}

extern "C" void kernel_launch(void* const* d_in, const int* in_sizes, int n_in,
                              void* d_out, int out_size, void* d_ws, size_t ws_size,
                              hipStream_t stream) {
    const float* x        = (const float*)d_in[0];
    const float* vocab    = (const float*)d_in[1];
    const float* nodef    = (const float*)d_in[2];
    const int*   src      = (const int*)d_in[3];
    const int*   dst      = (const int*)d_in[4];
    const float* W_lin1   = (const float*)d_in[5];
    const float* Wc1      = (const float*)d_in[6];
    const float* Wc2      = (const float*)d_in[7];
    const float* gat1_W   = (const float*)d_in[8];
    const float* gat1_al  = (const float*)d_in[9];
    const float* gat1_ar  = (const float*)d_in[10];
    const float* gat1_b   = (const float*)d_in[11];
    const float* gat2_W   = (const float*)d_in[12];
    const float* gat2_al  = (const float*)d_in[13];
    const float* gat2_ar  = (const float*)d_in[14];
    const float* gat2_b   = (const float*)d_in[15];
    const float* Wg1      = (const float*)d_in[16];
    const float* bg1      = (const float*)d_in[17];
    const float* W2       = (const float*)d_in[18];
    const float* W3       = (const float*)d_in[19];
    (void)in_sizes; (void)n_in; (void)ws_size;

    float* w = (float*)d_ws;
    size_t off = 0;
    auto alloc = [&](size_t n) { size_t o = off; off += (n + 63) & ~(size_t)63; return o; };
    size_t o_h2   = alloc(32);
    size_t o_prep = alloc(192);
    size_t o_er1  = alloc(2 * NN);
    size_t o_el2  = alloc(2 * NN);
    size_t o_er2  = alloc(2 * NN);
    size_t o_facc = alloc((size_t)2 * NN * 4);  // zero-region start
    size_t o_den2 = alloc(2 * NN);
    size_t o_q    = alloc(2 * NN);
    size_t o_A    = alloc(192);
    size_t o_zend = off;

    hipMemsetAsync(w + o_facc, 0, (o_zend - o_facc) * sizeof(float), stream);
    k_prep<<<1, 128, 0, stream>>>(gat1_W, gat1_al, gat1_ar, gat2_W, gat2_al, gat2_ar, w + o_prep);
    k_img<<<1, 256, 0, stream>>>(x, W_lin1, Wc1, Wc2, w + o_h2);

    dim3 gN((NN + 255) / 256, 2);
    dim3 gE((NE + 255) / 256, 2);
    dim3 gE4((4 * NE + 255) / 256, 2);
    k_er1<<<gN, 256, 0, stream>>>(nodef, w + o_prep, w + o_er1);
    k_e1<<<gE4, 256, 0, stream>>>(src, dst, nodef, w + o_prep, w + o_er1, w + o_facc);
    k_n1<<<gN, 256, 0, stream>>>(w + o_facc, gat1_W, gat1_b, w + o_prep, w + o_el2, w + o_er2);
    k_e2<<<gE, 256, 0, stream>>>(src, dst, w + o_el2, w + o_er2, w + o_den2);
    k_e3<<<gE, 256, 0, stream>>>(src, dst, w + o_el2, w + o_er2, w + o_den2, w + o_q);
    k_r<<<dim3(128, 2), 256, 0, stream>>>(w + o_facc, gat1_W, gat1_b, w + o_q, w + o_A);
    k_final<<<1, 128, 0, stream>>>(w + o_A, gat2_W, gat2_b, Wg1, bg1, w + o_h2, vocab,
                                   W2, W3, (float*)d_out, out_size);
}

// Round 6
// 263.129 us; speedup vs baseline: 4.3268x; 1.4384x over previous
//
#include <hip/hip_runtime.h>
#include <math.h>

#define NN 50000
#define NE 800000

// e1 chunking (facc4: 4 floats/node)
#define CH1 3125            // nodes/chunk -> 50 KB LDS
#define C1  16              // chunks (16*3125 = 50000)
#define NB1 16              // edge slices
#define SL1 (NE / NB1)      // 50000
// e2/e3 chunking (scalar/node)
#define CH2 12500           // 50 KB LDS
#define C2  4
#define NB2 64
#define SL2 (NE / NB2)      // 12500
// partial buffer: 2*C1*NB1*CH1*4 == 2*C2*NB2*CH2 == 6,400,000 floats

__device__ __forceinline__ float lrelu(float x, float s) { return x >= 0.f ? x : s * x; }

// prep[0..79]=u (W2h0@al2), prep[80..159]=v (W2h0@ar2), prep[160..162]=wl1, prep[163..165]=wr1
__global__ void k_prep(const float* __restrict__ W1, const float* __restrict__ al1,
                       const float* __restrict__ ar1, const float* __restrict__ W2,
                       const float* __restrict__ al2, const float* __restrict__ ar2,
                       float* __restrict__ prep) {
    int t = threadIdx.x;  // 128
    if (t < 80) {
        float u = 0.f, v = 0.f;
        for (int j = 0; j < 30; ++j) {
            float w = W2[t * 60 + j];  // head0 cols of [80, 60]
            u += w * al2[j];
            v += w * ar2[j];
        }
        prep[t] = u;
        prep[80 + t] = v;
    } else if (t < 83) {
        int c = t - 80;
        float a = 0.f, b = 0.f;
        for (int f = 0; f < 80; ++f) {
            float w = W1[c * 160 + f];  // head0 cols of [3, 160]
            a += w * al1[f];
            b += w * ar1[f];
        }
        prep[160 + c] = a;
        prep[163 + c] = b;
    }
}

// er1[g][n] = feat[g][n] . wr1
__global__ void k_er1(const float* __restrict__ nodef, const float* __restrict__ prep,
                      float* __restrict__ er1) {
    int g = blockIdx.y;
    int n = blockIdx.x * blockDim.x + threadIdx.x;
    if (n >= NN) return;
    const float* f = nodef + ((size_t)g * NN + n) * 3;
    er1[g * NN + n] = f[0] * prep[163] + f[1] * prep[164] + f[2] * prep[165];
}

// GAT1 sufficient stats via LDS chunks: block = (slice b, chunk c, graph g).
// sacc[rel][0..3] += w1*{f0,f1,f2,1} for edges with dst in chunk; flush to partials.
__global__ __launch_bounds__(1024) void k_e1c(const int* __restrict__ src,
                                              const int* __restrict__ dst,
                                              const float* __restrict__ nodef,
                                              const float* __restrict__ prep,
                                              const float* __restrict__ er1,
                                              float* __restrict__ P) {
    __shared__ float sacc[CH1 * 4];
    int b = blockIdx.x, c = blockIdx.y, g = blockIdx.z;
    for (int i = threadIdx.x; i < CH1 * 4; i += 1024) sacc[i] = 0.f;
    __syncthreads();
    int base = c * CH1;
    const int* sp = src + (size_t)g * NE;
    const int* dp = dst + (size_t)g * NE;
    const float* fp = nodef + (size_t)g * NN * 3;
    const float* erp = er1 + (size_t)g * NN;
    float wl0 = prep[160], wl1 = prep[161], wl2 = prep[162];
    int e0 = b * SL1;
    for (int e = e0 + threadIdx.x; e < e0 + SL1; e += 1024) {
        int d = dp[e];
        unsigned rel = (unsigned)(d - base);
        if (rel < CH1) {
            int s = sp[e];
            float f0 = fp[s * 3], f1 = fp[s * 3 + 1], f2 = fp[s * 3 + 2];
            float wv = __expf(lrelu(f0 * wl0 + f1 * wl1 + f2 * wl2 + erp[d], 0.2f));
            atomicAdd(&sacc[rel * 4 + 0], wv * f0);
            atomicAdd(&sacc[rel * 4 + 1], wv * f1);
            atomicAdd(&sacc[rel * 4 + 2], wv * f2);
            atomicAdd(&sacc[rel * 4 + 3], wv);
        }
    }
    __syncthreads();
    float* Pb = P + ((size_t)(g * C1 + c) * NB1 + b) * (CH1 * 4);
    for (int i = threadIdx.x; i < CH1 * 4; i += 1024) Pb[i] = sacc[i];
}

// den2 via LDS chunks (dst-chunked): sden[rel] += exp(lrelu(el2[s]+er2[d]))
__global__ __launch_bounds__(1024) void k_e2c(const int* __restrict__ src,
                                              const int* __restrict__ dst,
                                              const float* __restrict__ el2,
                                              const float* __restrict__ er2,
                                              float* __restrict__ P) {
    __shared__ float sden[CH2];
    int b = blockIdx.x, c = blockIdx.y, g = blockIdx.z;
    for (int i = threadIdx.x; i < CH2; i += 1024) sden[i] = 0.f;
    __syncthreads();
    int base = c * CH2;
    const int* sp = src + (size_t)g * NE;
    const int* dp = dst + (size_t)g * NE;
    const float* el = el2 + (size_t)g * NN;
    const float* er = er2 + (size_t)g * NN;
    int e0 = b * SL2;
    for (int e = e0 + threadIdx.x; e < e0 + SL2; e += 1024) {
        int d = dp[e];
        unsigned rel = (unsigned)(d - base);
        if (rel < CH2) {
            float wv = __expf(lrelu(el[sp[e]] + er[d], 0.2f));
            atomicAdd(&sden[rel], wv);
        }
    }
    __syncthreads();
    float* Pb = P + ((size_t)(g * C2 + c) * NB2 + b) * CH2;
    for (int i = threadIdx.x; i < CH2; i += 1024) Pb[i] = sden[i];
}

// q via LDS chunks (src-chunked): sq[rel] += exp(lrelu(el2[s]+er2[d])) * invden2[d]
__global__ __launch_bounds__(1024) void k_e3c(const int* __restrict__ src,
                                              const int* __restrict__ dst,
                                              const float* __restrict__ el2,
                                              const float* __restrict__ er2,
                                              const float* __restrict__ invden,
                                              float* __restrict__ P) {
    __shared__ float sq[CH2];
    int b = blockIdx.x, c = blockIdx.y, g = blockIdx.z;
    for (int i = threadIdx.x; i < CH2; i += 1024) sq[i] = 0.f;
    __syncthreads();
    int base = c * CH2;
    const int* sp = src + (size_t)g * NE;
    const int* dp = dst + (size_t)g * NE;
    const float* el = el2 + (size_t)g * NN;
    const float* er = er2 + (size_t)g * NN;
    const float* iv = invden + (size_t)g * NN;
    int e0 = b * SL2;
    for (int e = e0 + threadIdx.x; e < e0 + SL2; e += 1024) {
        int s = sp[e];
        unsigned rel = (unsigned)(s - base);
        if (rel < CH2) {
            int d = dp[e];
            float wv = __expf(lrelu(el[s] + er[d], 0.2f));
            atomicAdd(&sq[rel], wv * iv[d]);
        }
    }
    __syncthreads();
    float* Pb = P + ((size_t)(g * C2 + c) * NB2 + b) * CH2;
    for (int i = threadIdx.x; i < CH2; i += 1024) Pb[i] = sq[i];
}

// Generic partial reduce: out[g][c*CHW+j] = sum_b P[((g*C+c)*NB+b)*CHW + j]
// (C*CHW == NN*W so out is laid out [g][node*W+comp].) inv: store reciprocal.
__global__ void k_red(const float* __restrict__ P, float* __restrict__ out,
                      int C, int NB, int CHW, int inv) {
    int T = 2 * C * CHW;
    int idx = blockIdx.x * blockDim.x + threadIdx.x;
    if (idx >= T) return;
    int g = idx / (C * CHW);
    int rem = idx - g * (C * CHW);
    int c = rem / CHW;
    int j = rem - c * CHW;
    const float* Pp = P + ((size_t)(g * C + c) * NB) * CHW + j;
    float s = 0.f;
    for (int b = 0; b < NB; ++b) s += Pp[(size_t)b * CHW];
    out[idx] = inv ? (s != 0.f ? 1.f / s : 0.f) : s;
}

// Per node: g1 = relu(facc.xyz/facc.w @ W1h0 + b1); el2 = g1.u, er2 = g1.v
__global__ void k_n1(const float* __restrict__ facc4, const float* __restrict__ W1,
                     const float* __restrict__ b1, const float* __restrict__ prep,
                     float* __restrict__ el2, float* __restrict__ er2) {
    __shared__ float sW[240], sB[80], sU[80], sV[80];
    for (int t = threadIdx.x; t < 80; t += blockDim.x) {
        sW[t] = W1[t];
        sW[80 + t] = W1[160 + t];
        sW[160 + t] = W1[320 + t];
        sB[t] = b1[t];
        sU[t] = prep[t];
        sV[t] = prep[80 + t];
    }
    __syncthreads();
    int g = blockIdx.y;
    int n = blockIdx.x * blockDim.x + threadIdx.x;
    if (n >= NN) return;
    float4 fa = *(const float4*)(facc4 + ((size_t)g * NN + n) * 4);
    float inv = fa.w != 0.f ? 1.f / fa.w : 0.f;
    float c0 = fa.x * inv, c1 = fa.y * inv, c2 = fa.z * inv;
    float el = 0.f, er = 0.f;
    #pragma unroll
    for (int f = 0; f < 80; ++f) {
        float gg = c0 * sW[f] + c1 * sW[80 + f] + c2 * sW[160 + f] + sB[f];
        gg = gg > 0.f ? gg : 0.f;
        el += gg * sU[f];
        er += gg * sV[f];
    }
    el2[g * NN + n] = el;
    er2[g * NN + n] = er;
}

// A[g][0..79] = sum_n q[n] * g1[n]  — register accumulation over 128-node LDS tiles.
#define RT 128
__global__ void k_r(const float* __restrict__ facc4, const float* __restrict__ W1,
                    const float* __restrict__ b1, const float* __restrict__ q,
                    float* __restrict__ A) {
    __shared__ float4 sF[RT];
    __shared__ float sQ[RT];
    __shared__ float sW[240], sB[80];
    __shared__ float sA[240];
    int t = threadIdx.x;
    for (int i = t; i < 80; i += 256) {
        sW[i] = W1[i];
        sW[80 + i] = W1[160 + i];
        sW[160 + i] = W1[320 + i];
        sB[i] = b1[i];
    }
    int g = blockIdx.y;
    int grp = t / 80, f = t - grp * 80;
    float acc = 0.f;
    for (int n0 = blockIdx.x * RT; n0 < NN; n0 += gridDim.x * RT) {
        __syncthreads();
        if (t < RT) {
            int n = n0 + t;
            sF[t] = (n < NN) ? *(const float4*)(facc4 + ((size_t)g * NN + n) * 4)
                             : make_float4(0.f, 0.f, 0.f, 0.f);
        } else if (t < 2 * RT) {
            int n = n0 + t - RT;
            sQ[t - RT] = (n < NN) ? q[g * NN + n] : 0.f;
        }
        __syncthreads();
        if (grp < 3) {
            for (int i = grp; i < RT; i += 3) {
                float qn = sQ[i];
                if (qn == 0.f) continue;
                float4 fa = sF[i];
                float inv = fa.w != 0.f ? 1.f / fa.w : 0.f;
                float c0 = fa.x * inv, c1 = fa.y * inv, c2 = fa.z * inv;
                float gg = c0 * sW[f] + c1 * sW[80 + f] + c2 * sW[160 + f] + sB[f];
                gg = gg > 0.f ? gg : 0.f;
                acc += qn * gg;
            }
        }
    }
    if (grp < 3) sA[t] = acc;
    __syncthreads();
    if (t < 80) atomicAdd(&A[g * 80 + t], sA[t] + sA[80 + t] + sA[160 + t]);
}

// Image branch: emb = x@W_lin1 [2,30]; h = lrelu(Wc1@emb); h2 = lrelu(Wc2@h) [30]
__global__ void k_img(const float* __restrict__ x, const float* __restrict__ W1,
                      const float* __restrict__ Wc1, const float* __restrict__ Wc2,
                      float* __restrict__ h2out) {
    __shared__ float part[240];
    __shared__ float emb[60];
    __shared__ float hh[80 * 30];
    int t = threadIdx.x;  // 256
    if (t < 240) {
        int g = t / 120, k = (t / 4) % 30, q = t % 4;
        float acc = 0.f;
        const float* xp = x + g * 4096 + q * 1024;
        for (int c = 0; c < 1024; ++c) acc += xp[c] * W1[(q * 1024 + c) * 30 + k];
        part[t] = acc;
    }
    __syncthreads();
    if (t < 60) {
        int g = t / 30, k = t % 30;
        int b = g * 120 + k * 4;
        emb[t] = part[b] + part[b + 1] + part[b + 2] + part[b + 3];
    }
    __syncthreads();
    for (int p = t; p < 2400; p += 256) {
        int i = p / 30, j = p % 30;
        float v = Wc1[i * 2 + 0] * emb[j] + Wc1[i * 2 + 1] * emb[30 + j];
        hh[p] = lrelu(v, 0.01f);
    }
    __syncthreads();
    if (t < 30) {
        float acc = 0.f;
        for (int i = 0; i < 80; ++i) acc += Wc2[i] * hh[i * 30 + t];
        h2out[t] = lrelu(acc, 0.01f);
    }
}

// Final head
__global__ void k_final(const float* __restrict__ A, const float* __restrict__ W2g,
                        const float* __restrict__ b2, const float* __restrict__ Wg1,
                        const float* __restrict__ bg1, const float* __restrict__ h2,
                        const float* __restrict__ vocab, const float* __restrict__ W2f,
                        const float* __restrict__ W3, float* __restrict__ out, int out_size) {
    __shared__ float a[60];
    __shared__ float hc[70];
    __shared__ float tt[80];
    __shared__ float lp[2];
    int t = threadIdx.x;  // 128
    if (t < 60) {
        int i = t / 30, j = t % 30;
        float acc = 0.f;
        for (int f = 0; f < 80; ++f) acc += A[i * 80 + f] * W2g[f * 60 + j];
        a[t] = acc * (1.f / NN) + b2[j];
    }
    __syncthreads();
    if (t < 30) {
        float acc = bg1[t];
        for (int j = 0; j < 60; ++j) acc += a[j] * Wg1[j * 30 + t];
        hc[t] = acc;
        hc[30 + t] = h2[t];
        if (t < 10) hc[60 + t] = vocab[t];
    }
    __syncthreads();
    if (t < 80) {
        float acc = 0.f;
        for (int qd = 0; qd < 70; ++qd) acc += hc[qd] * W2f[qd * 80 + t];
        tt[t] = acc;
    }
    __syncthreads();
    if (t < 2) {
        float acc = 0.f;
        for (int p = 0; p < 80; ++p) acc += tt[p] * W3[p * 2 + t];
        lp[t] = acc;
    }
    __syncthreads();
    if (t == 0) {
        float m = fmaxf(lp[0], lp[1]);
        float lse = m + logf(expf(lp[0] - m) + expf(lp[1] - m));
        out[0] = lp[0] - lse;
        out[1] = lp[1] - lse;
    }
    for (int i = 2 + t; i < out_size; i += blockDim.x) out[i] = 0.f;
}

extern "C" void kernel_launch(void* const* d_in, const int* in_sizes, int n_in,
                              void* d_out, int out_size, void* d_ws, size_t ws_size,
                              hipStream_t stream) {
    const float* x        = (const float*)d_in[0];
    const float* vocab    = (const float*)d_in[1];
    const float* nodef    = (const float*)d_in[2];
    const int*   src      = (const int*)d_in[3];
    const int*   dst      = (const int*)d_in[4];
    const float* W_lin1   = (const float*)d_in[5];
    const float* Wc1      = (const float*)d_in[6];
    const float* Wc2      = (const float*)d_in[7];
    const float* gat1_W   = (const float*)d_in[8];
    const float* gat1_al  = (const float*)d_in[9];
    const float* gat1_ar  = (const float*)d_in[10];
    const float* gat1_b   = (const float*)d_in[11];
    const float* gat2_W   = (const float*)d_in[12];
    const float* gat2_al  = (const float*)d_in[13];
    const float* gat2_ar  = (const float*)d_in[14];
    const float* gat2_b   = (const float*)d_in[15];
    const float* Wg1      = (const float*)d_in[16];
    const float* bg1      = (const float*)d_in[17];
    const float* W2       = (const float*)d_in[18];
    const float* W3       = (const float*)d_in[19];
    (void)in_sizes; (void)n_in; (void)ws_size;

    float* w = (float*)d_ws;
    size_t off = 0;
    auto alloc = [&](size_t n) { size_t o = off; off += (n + 63) & ~(size_t)63; return o; };
    size_t o_h2   = alloc(32);
    size_t o_prep = alloc(192);
    size_t o_er1  = alloc(2 * NN);
    size_t o_el2  = alloc(2 * NN);
    size_t o_er2  = alloc(2 * NN);
    size_t o_facc = alloc((size_t)2 * NN * 4);
    size_t o_iden = alloc(2 * NN);
    size_t o_q    = alloc(2 * NN);
    size_t o_A    = alloc(192);
    size_t o_P    = alloc((size_t)2 * C1 * NB1 * CH1 * 4);  // 6.4M floats, shared by all passes

    hipMemsetAsync(w + o_A, 0, 192 * sizeof(float), stream);
    k_prep<<<1, 128, 0, stream>>>(gat1_W, gat1_al, gat1_ar, gat2_W, gat2_al, gat2_ar, w + o_prep);
    k_img<<<1, 256, 0, stream>>>(x, W_lin1, Wc1, Wc2, w + o_h2);

    dim3 gN((NN + 255) / 256, 2);
    k_er1<<<gN, 256, 0, stream>>>(nodef, w + o_prep, w + o_er1);

    k_e1c<<<dim3(NB1, C1, 2), 1024, 0, stream>>>(src, dst, nodef, w + o_prep, w + o_er1, w + o_P);
    k_red<<<(2 * NN * 4 + 1023) / 1024, 1024, 0, stream>>>(w + o_P, w + o_facc,
                                                           C1, NB1, CH1 * 4, 0);
    k_n1<<<gN, 256, 0, stream>>>(w + o_facc, gat1_W, gat1_b, w + o_prep, w + o_el2, w + o_er2);

    k_e2c<<<dim3(NB2, C2, 2), 1024, 0, stream>>>(src, dst, w + o_el2, w + o_er2, w + o_P);
    k_red<<<(2 * NN + 1023) / 1024, 1024, 0, stream>>>(w + o_P, w + o_iden, C2, NB2, CH2, 1);

    k_e3c<<<dim3(NB2, C2, 2), 1024, 0, stream>>>(src, dst, w + o_el2, w + o_er2,
                                                 w + o_iden, w + o_P);
    k_red<<<(2 * NN + 1023) / 1024, 1024, 0, stream>>>(w + o_P, w + o_q, C2, NB2, CH2, 0);

    k_r<<<dim3(128, 2), 256, 0, stream>>>(w + o_facc, gat1_W, gat1_b, w + o_q, w + o_A);
    k_final<<<1, 128, 0, stream>>>(w + o_A, gat2_W, gat2_b, Wg1, bg1, w + o_h2, vocab,
                                   W2, W3, (float*)d_out, out_size);
}

// Round 7
// 206.635 us; speedup vs baseline: 5.5097x; 1.2734x over previous
//
#include <hip/hip_runtime.h>
#include <math.h>

#define NN 50000
#define NE 800000

// e1 chunking (facc4: 4 floats/node)
#define CH1 3125            // nodes/chunk -> 50 KB LDS
#define C1  16
#define NB1 16
#define SL1 (NE / NB1)      // 50000
// e2/e3 chunking (scalar/node)
#define CH2 12500           // 50 KB LDS
#define C2  4
#define NB2 64
#define SL2 (NE / NB2)      // 12500

__device__ __forceinline__ float lrelu(float x, float s) { return x >= 0.f ? x : s * x; }

// prep[0..79]=u (W2h0@al2), prep[80..159]=v (W2h0@ar2), prep[160..162]=wl1, prep[163..165]=wr1
__global__ void k_prep(const float* __restrict__ W1, const float* __restrict__ al1,
                       const float* __restrict__ ar1, const float* __restrict__ W2,
                       const float* __restrict__ al2, const float* __restrict__ ar2,
                       float* __restrict__ prep) {
    int t = threadIdx.x;  // 128
    if (t < 80) {
        float u = 0.f, v = 0.f;
        for (int j = 0; j < 30; ++j) {
            float w = W2[t * 60 + j];  // head0 cols of [80, 60]
            u += w * al2[j];
            v += w * ar2[j];
        }
        prep[t] = u;
        prep[80 + t] = v;
    } else if (t < 83) {
        int c = t - 80;
        float a = 0.f, b = 0.f;
        for (int f = 0; f < 80; ++f) {
            float w = W1[c * 160 + f];  // head0 cols of [3, 160]
            a += w * al1[f];
            b += w * ar1[f];
        }
        prep[160 + c] = a;
        prep[163 + c] = b;
    }
}

// Per node: feat4 = {f0, f1, f2, el1}; er1 = f.wr1
__global__ void k_pack(const float* __restrict__ nodef, const float* __restrict__ prep,
                       float* __restrict__ feat4, float* __restrict__ er1) {
    int g = blockIdx.y;
    int n = blockIdx.x * blockDim.x + threadIdx.x;
    if (n >= NN) return;
    const float* f = nodef + ((size_t)g * NN + n) * 3;
    float f0 = f[0], f1 = f[1], f2 = f[2];
    *(float4*)(feat4 + ((size_t)g * NN + n) * 4) =
        make_float4(f0, f1, f2, f0 * prep[160] + f1 * prep[161] + f2 * prep[162]);
    er1[g * NN + n] = f0 * prep[163] + f1 * prep[164] + f2 * prep[165];
}

// GAT1 sufficient stats via LDS chunks: block = (slice b, chunk c, graph g).
__global__ __launch_bounds__(1024) void k_e1c(const int* __restrict__ src,
                                              const int* __restrict__ dst,
                                              const float* __restrict__ feat4,
                                              const float* __restrict__ er1,
                                              float* __restrict__ P) {
    __shared__ float sacc[CH1 * 4];
    int b = blockIdx.x, c = blockIdx.y, g = blockIdx.z;
    for (int i = threadIdx.x; i < CH1 * 4; i += 1024) sacc[i] = 0.f;
    __syncthreads();
    int base = c * CH1;
    const int* sp = src + (size_t)g * NE;
    const int* dp = dst + (size_t)g * NE;
    const float* f4 = feat4 + (size_t)g * NN * 4;
    const float* erp = er1 + (size_t)g * NN;
    int e0 = b * SL1;
    for (int e = e0 + threadIdx.x; e < e0 + SL1; e += 1024) {
        int d = dp[e];
        unsigned rel = (unsigned)(d - base);
        if (rel < CH1) {
            int s = sp[e];
            float4 F = *(const float4*)(f4 + (size_t)s * 4);
            float wv = __expf(lrelu(F.w + erp[d], 0.2f));
            atomicAdd(&sacc[rel * 4 + 0], wv * F.x);
            atomicAdd(&sacc[rel * 4 + 1], wv * F.y);
            atomicAdd(&sacc[rel * 4 + 2], wv * F.z);
            atomicAdd(&sacc[rel * 4 + 3], wv);
        }
    }
    __syncthreads();
    float* Pb = P + ((size_t)(g * C1 + c) * NB1 + b) * (CH1 * 4);
    for (int i = threadIdx.x; i < CH1 * 4; i += 1024) Pb[i] = sacc[i];
}

// den2 via LDS chunks (dst-chunked): sden[rel] += exp(lrelu(el2[s]+er2[d]))
__global__ __launch_bounds__(1024) void k_e2c(const int* __restrict__ src,
                                              const int* __restrict__ dst,
                                              const float* __restrict__ el2,
                                              const float* __restrict__ er2iv,
                                              float* __restrict__ P) {
    __shared__ float sden[CH2];
    int b = blockIdx.x, c = blockIdx.y, g = blockIdx.z;
    for (int i = threadIdx.x; i < CH2; i += 1024) sden[i] = 0.f;
    __syncthreads();
    int base = c * CH2;
    const int* sp = src + (size_t)g * NE;
    const int* dp = dst + (size_t)g * NE;
    const float* el = el2 + (size_t)g * NN;
    const float* er = er2iv + (size_t)g * NN * 2;
    int e0 = b * SL2;
    for (int e = e0 + threadIdx.x; e < e0 + SL2; e += 1024) {
        int d = dp[e];
        unsigned rel = (unsigned)(d - base);
        if (rel < CH2) {
            float wv = __expf(lrelu(el[sp[e]] + er[2 * d], 0.2f));
            atomicAdd(&sden[rel], wv);
        }
    }
    __syncthreads();
    float* Pb = P + ((size_t)(g * C2 + c) * NB2 + b) * CH2;
    for (int i = threadIdx.x; i < CH2; i += 1024) Pb[i] = sden[i];
}

// q via LDS chunks (src-chunked): sq[rel] += exp(lrelu(el2[s]+er2[d])) * invden2[d]
__global__ __launch_bounds__(1024) void k_e3c(const int* __restrict__ src,
                                              const int* __restrict__ dst,
                                              const float* __restrict__ el2,
                                              const float* __restrict__ er2iv,
                                              float* __restrict__ P) {
    __shared__ float sq[CH2];
    int b = blockIdx.x, c = blockIdx.y, g = blockIdx.z;
    for (int i = threadIdx.x; i < CH2; i += 1024) sq[i] = 0.f;
    __syncthreads();
    int base = c * CH2;
    const int* sp = src + (size_t)g * NE;
    const int* dp = dst + (size_t)g * NE;
    const float* el = el2 + (size_t)g * NN;
    const float* er = er2iv + (size_t)g * NN * 2;
    int e0 = b * SL2;
    for (int e = e0 + threadIdx.x; e < e0 + SL2; e += 1024) {
        int s = sp[e];
        unsigned rel = (unsigned)(s - base);
        if (rel < CH2) {
            float2 EI = *(const float2*)(er + 2 * dp[e]);
            float wv = __expf(lrelu(el[s] + EI.x, 0.2f));
            atomicAdd(&sq[rel], wv * EI.y);
        }
    }
    __syncthreads();
    float* Pb = P + ((size_t)(g * C2 + c) * NB2 + b) * CH2;
    for (int i = threadIdx.x; i < CH2; i += 1024) Pb[i] = sq[i];
}

// Generic partial reduce: sums NB partials; writes out[idx*ostride+ooff] (optionally 1/s).
__global__ void k_red(const float* __restrict__ P, float* __restrict__ out,
                      int C, int NB, int CHW, int inv, int ostride, int ooff) {
    int T = 2 * C * CHW;
    int idx = blockIdx.x * blockDim.x + threadIdx.x;
    if (idx >= T) return;
    int gc = idx / CHW;
    int j = idx - gc * CHW;
    const float* Pp = P + ((size_t)gc * NB) * CHW + j;
    float s = 0.f;
    for (int b = 0; b < NB; ++b) s += Pp[(size_t)b * CHW];
    out[(size_t)idx * ostride + ooff] = inv ? (s != 0.f ? 1.f / s : 0.f) : s;
}

// Per node: g1 = relu(facc.xyz/facc.w @ W1h0 + b1); el2 = g1.u, er2iv[2n] = g1.v
__global__ void k_n1(const float* __restrict__ facc4, const float* __restrict__ W1,
                     const float* __restrict__ b1, const float* __restrict__ prep,
                     float* __restrict__ el2, float* __restrict__ er2iv) {
    __shared__ float sW[240], sB[80], sU[80], sV[80];
    for (int t = threadIdx.x; t < 80; t += blockDim.x) {
        sW[t] = W1[t];
        sW[80 + t] = W1[160 + t];
        sW[160 + t] = W1[320 + t];
        sB[t] = b1[t];
        sU[t] = prep[t];
        sV[t] = prep[80 + t];
    }
    __syncthreads();
    int g = blockIdx.y;
    int n = blockIdx.x * blockDim.x + threadIdx.x;
    if (n >= NN) return;
    float4 fa = *(const float4*)(facc4 + ((size_t)g * NN + n) * 4);
    float inv = fa.w != 0.f ? 1.f / fa.w : 0.f;
    float c0 = fa.x * inv, c1 = fa.y * inv, c2 = fa.z * inv;
    float el = 0.f, er = 0.f;
    #pragma unroll
    for (int f = 0; f < 80; ++f) {
        float gg = c0 * sW[f] + c1 * sW[80 + f] + c2 * sW[160 + f] + sB[f];
        gg = gg > 0.f ? gg : 0.f;
        el += gg * sU[f];
        er += gg * sV[f];
    }
    el2[g * NN + n] = el;
    er2iv[((size_t)g * NN + n) * 2] = er;
}

// A[g][0..79] = sum_n q[n] * g1[n]  — register accumulation over 128-node LDS tiles.
#define RT 128
__global__ void k_r(const float* __restrict__ facc4, const float* __restrict__ W1,
                    const float* __restrict__ b1, const float* __restrict__ q,
                    float* __restrict__ A) {
    __shared__ float4 sF[RT];
    __shared__ float sQ[RT];
    __shared__ float sW[240], sB[80];
    __shared__ float sA[240];
    int t = threadIdx.x;
    for (int i = t; i < 80; i += 256) {
        sW[i] = W1[i];
        sW[80 + i] = W1[160 + i];
        sW[160 + i] = W1[320 + i];
        sB[i] = b1[i];
    }
    int g = blockIdx.y;
    int grp = t / 80, f = t - grp * 80;
    float acc = 0.f;
    for (int n0 = blockIdx.x * RT; n0 < NN; n0 += gridDim.x * RT) {
        __syncthreads();
        if (t < RT) {
            int n = n0 + t;
            sF[t] = (n < NN) ? *(const float4*)(facc4 + ((size_t)g * NN + n) * 4)
                             : make_float4(0.f, 0.f, 0.f, 0.f);
        } else if (t < 2 * RT) {
            int n = n0 + t - RT;
            sQ[t - RT] = (n < NN) ? q[g * NN + n] : 0.f;
        }
        __syncthreads();
        if (grp < 3) {
            for (int i = grp; i < RT; i += 3) {
                float qn = sQ[i];
                if (qn == 0.f) continue;
                float4 fa = sF[i];
                float inv = fa.w != 0.f ? 1.f / fa.w : 0.f;
                float c0 = fa.x * inv, c1 = fa.y * inv, c2 = fa.z * inv;
                float gg = c0 * sW[f] + c1 * sW[80 + f] + c2 * sW[160 + f] + sB[f];
                gg = gg > 0.f ? gg : 0.f;
                acc += qn * gg;
            }
        }
    }
    if (grp < 3) sA[t] = acc;
    __syncthreads();
    if (t < 80) atomicAdd(&A[g * 80 + t], sA[t] + sA[80 + t] + sA[160 + t]);
}

// Image matmul: emb_acc[g][k] += x[g] @ W_lin1[:,k], 64 blocks each owning 64 rows.
__global__ void k_img1(const float* __restrict__ x, const float* __restrict__ W1,
                       float* __restrict__ emb_acc) {
    __shared__ float part[8][64];  // [rq][g*30+k] padded
    int t = threadIdx.x;  // 256
    int kk = t & 31, rq = t >> 5;
    int r0 = blockIdx.x * 64;
    float a0 = 0.f, a1 = 0.f;
    if (kk < 30) {
        for (int i = 0; i < 8; ++i) {
            int r = r0 + rq * 8 + i;
            float wv = W1[r * 30 + kk];
            a0 += x[r] * wv;
            a1 += x[4096 + r] * wv;
        }
    }
    part[rq][kk] = a0;
    part[rq][32 + kk] = a1;
    __syncthreads();
    if (t < 60) {
        int g = t / 30, k = t - g * 30;
        float s = 0.f;
        #pragma unroll
        for (int rr = 0; rr < 8; ++rr) s += part[rr][g * 32 + k];
        atomicAdd(&emb_acc[g * 30 + k], s);
    }
}

// Image conv tail: h = lrelu(Wc1@emb); h2 = lrelu(Wc2@h) [30]
__global__ void k_img2(const float* __restrict__ emb_acc, const float* __restrict__ Wc1,
                       const float* __restrict__ Wc2, float* __restrict__ h2out) {
    __shared__ float emb[60];
    __shared__ float hh[80 * 30];
    int t = threadIdx.x;  // 256
    if (t < 60) emb[t] = emb_acc[t];
    __syncthreads();
    for (int p = t; p < 2400; p += 256) {
        int i = p / 30, j = p % 30;
        float v = Wc1[i * 2 + 0] * emb[j] + Wc1[i * 2 + 1] * emb[30 + j];
        hh[p] = lrelu(v, 0.01f);
    }
    __syncthreads();
    if (t < 30) {
        float acc = 0.f;
        for (int i = 0; i < 80; ++i) acc += Wc2[i] * hh[i * 30 + t];
        h2out[t] = lrelu(acc, 0.01f);
    }
}

// Final head
__global__ void k_final(const float* __restrict__ A, const float* __restrict__ W2g,
                        const float* __restrict__ b2, const float* __restrict__ Wg1,
                        const float* __restrict__ bg1, const float* __restrict__ h2,
                        const float* __restrict__ vocab, const float* __restrict__ W2f,
                        const float* __restrict__ W3, float* __restrict__ out, int out_size) {
    __shared__ float a[60];
    __shared__ float hc[70];
    __shared__ float tt[80];
    __shared__ float lp[2];
    int t = threadIdx.x;  // 128
    if (t < 60) {
        int i = t / 30, j = t % 30;
        float acc = 0.f;
        for (int f = 0; f < 80; ++f) acc += A[i * 80 + f] * W2g[f * 60 + j];
        a[t] = acc * (1.f / NN) + b2[j];
    }
    __syncthreads();
    if (t < 30) {
        float acc = bg1[t];
        for (int j = 0; j < 60; ++j) acc += a[j] * Wg1[j * 30 + t];
        hc[t] = acc;
        hc[30 + t] = h2[t];
        if (t < 10) hc[60 + t] = vocab[t];
    }
    __syncthreads();
    if (t < 80) {
        float acc = 0.f;
        for (int qd = 0; qd < 70; ++qd) acc += hc[qd] * W2f[qd * 80 + t];
        tt[t] = acc;
    }
    __syncthreads();
    if (t < 2) {
        float acc = 0.f;
        for (int p = 0; p < 80; ++p) acc += tt[p] * W3[p * 2 + t];
        lp[t] = acc;
    }
    __syncthreads();
    if (t == 0) {
        float m = fmaxf(lp[0], lp[1]);
        float lse = m + logf(expf(lp[0] - m) + expf(lp[1] - m));
        out[0] = lp[0] - lse;
        out[1] = lp[1] - lse;
    }
    for (int i = 2 + t; i < out_size; i += blockDim.x) out[i] = 0.f;
}

extern "C" void kernel_launch(void* const* d_in, const int* in_sizes, int n_in,
                              void* d_out, int out_size, void* d_ws, size_t ws_size,
                              hipStream_t stream) {
    const float* x        = (const float*)d_in[0];
    const float* vocab    = (const float*)d_in[1];
    const float* nodef    = (const float*)d_in[2];
    const int*   src      = (const int*)d_in[3];
    const int*   dst      = (const int*)d_in[4];
    const float* W_lin1   = (const float*)d_in[5];
    const float* Wc1      = (const float*)d_in[6];
    const float* Wc2      = (const float*)d_in[7];
    const float* gat1_W   = (const float*)d_in[8];
    const float* gat1_al  = (const float*)d_in[9];
    const float* gat1_ar  = (const float*)d_in[10];
    const float* gat1_b   = (const float*)d_in[11];
    const float* gat2_W   = (const float*)d_in[12];
    const float* gat2_al  = (const float*)d_in[13];
    const float* gat2_ar  = (const float*)d_in[14];
    const float* gat2_b   = (const float*)d_in[15];
    const float* Wg1      = (const float*)d_in[16];
    const float* bg1      = (const float*)d_in[17];
    const float* W2       = (const float*)d_in[18];
    const float* W3       = (const float*)d_in[19];
    (void)in_sizes; (void)n_in; (void)ws_size;

    float* w = (float*)d_ws;
    size_t off = 0;
    auto alloc = [&](size_t n) { size_t o = off; off += (n + 63) & ~(size_t)63; return o; };
    size_t o_emb  = alloc(64);   // zeroed
    size_t o_A    = alloc(192);  // zeroed (contiguous with o_emb)
    size_t o_h2   = alloc(32);
    size_t o_prep = alloc(192);
    size_t o_feat = alloc((size_t)2 * NN * 4);
    size_t o_er1  = alloc(2 * NN);
    size_t o_el2  = alloc(2 * NN);
    size_t o_eriv = alloc((size_t)2 * NN * 2);
    size_t o_facc = alloc((size_t)2 * NN * 4);
    size_t o_q    = alloc(2 * NN);
    size_t o_P    = alloc((size_t)2 * C1 * NB1 * CH1 * 4);

    hipMemsetAsync(w + o_emb, 0, 256 * sizeof(float), stream);
    k_prep<<<1, 128, 0, stream>>>(gat1_W, gat1_al, gat1_ar, gat2_W, gat2_al, gat2_ar, w + o_prep);
    k_img1<<<64, 256, 0, stream>>>(x, W_lin1, w + o_emb);
    k_img2<<<1, 256, 0, stream>>>(w + o_emb, Wc1, Wc2, w + o_h2);

    dim3 gN((NN + 255) / 256, 2);
    k_pack<<<gN, 256, 0, stream>>>(nodef, w + o_prep, w + o_feat, w + o_er1);

    k_e1c<<<dim3(NB1, C1, 2), 1024, 0, stream>>>(src, dst, w + o_feat, w + o_er1, w + o_P);
    k_red<<<(2 * NN * 4 + 1023) / 1024, 1024, 0, stream>>>(w + o_P, w + o_facc,
                                                           C1, NB1, CH1 * 4, 0, 1, 0);
    k_n1<<<gN, 256, 0, stream>>>(w + o_facc, gat1_W, gat1_b, w + o_prep,
                                 w + o_el2, w + o_eriv);

    k_e2c<<<dim3(NB2, C2, 2), 1024, 0, stream>>>(src, dst, w + o_el2, w + o_eriv, w + o_P);
    k_red<<<(2 * NN + 1023) / 1024, 1024, 0, stream>>>(w + o_P, w + o_eriv,
                                                       C2, NB2, CH2, 1, 2, 1);

    k_e3c<<<dim3(NB2, C2, 2), 1024, 0, stream>>>(src, dst, w + o_el2, w + o_eriv, w + o_P);
    k_red<<<(2 * NN + 1023) / 1024, 1024, 0, stream>>>(w + o_P, w + o_q,
                                                       C2, NB2, CH2, 0, 1, 0);

    k_r<<<dim3(128, 2), 256, 0, stream>>>(w + o_facc, gat1_W, gat1_b, w + o_q, w + o_A);
    k_final<<<1, 128, 0, stream>>>(w + o_A, gat2_W, gat2_b, Wg1, bg1, w + o_h2, vocab,
                                   W2, W3, (float*)d_out, out_size);
}

// Round 8
// 201.046 us; speedup vs baseline: 5.6629x; 1.0278x over previous
//
#include <hip/hip_runtime.h>
#include <math.h>

#define NN 50000
#define NE 800000

// e1 chunking (facc4: 4 floats/node)
#define CH1 3125            // nodes/chunk -> 50 KB LDS
#define C1  16
#define NB1 8
#define SL1 (NE / NB1)      // 100000
// e2/e3 chunking (scalar/node)
#define CH2 12500           // 50 KB LDS
#define C2  4
#define NB2 32
#define SL2 (NE / NB2)      // 25000
#define QCAP 128            // per-wave compaction queue

__device__ __forceinline__ float lrelu(float x, float s) { return x >= 0.f ? x : s * x; }

// prep[0..79]=u (W2h0@al2), prep[80..159]=v (W2h0@ar2), prep[160..162]=wl1, prep[163..165]=wr1
__global__ void k_prep(const float* __restrict__ W1, const float* __restrict__ al1,
                       const float* __restrict__ ar1, const float* __restrict__ W2,
                       const float* __restrict__ al2, const float* __restrict__ ar2,
                       float* __restrict__ prep) {
    int t = threadIdx.x;  // 128
    if (t < 80) {
        float u = 0.f, v = 0.f;
        for (int j = 0; j < 30; ++j) {
            float w = W2[t * 60 + j];  // head0 cols of [80, 60]
            u += w * al2[j];
            v += w * ar2[j];
        }
        prep[t] = u;
        prep[80 + t] = v;
    } else if (t < 83) {
        int c = t - 80;
        float a = 0.f, b = 0.f;
        for (int f = 0; f < 80; ++f) {
            float w = W1[c * 160 + f];  // head0 cols of [3, 160]
            a += w * al1[f];
            b += w * ar1[f];
        }
        prep[160 + c] = a;
        prep[163 + c] = b;
    }
}

// Per node: feat4 = {f0, f1, f2, el1}; er1 = f.wr1
__global__ void k_pack(const float* __restrict__ nodef, const float* __restrict__ prep,
                       float* __restrict__ feat4, float* __restrict__ er1) {
    int g = blockIdx.y;
    int n = blockIdx.x * blockDim.x + threadIdx.x;
    if (n >= NN) return;
    const float* f = nodef + ((size_t)g * NN + n) * 3;
    float f0 = f[0], f1 = f[1], f2 = f[2];
    *(float4*)(feat4 + ((size_t)g * NN + n) * 4) =
        make_float4(f0, f1, f2, f0 * prep[160] + f1 * prep[161] + f2 * prep[162]);
    er1[g * NN + n] = f0 * prep[163] + f1 * prep[164] + f2 * prep[165];
}

// GAT1 sufficient stats via LDS chunks + wave ballot-compaction.
__global__ __launch_bounds__(1024) void k_e1c(const int* __restrict__ src,
                                              const int* __restrict__ dst,
                                              const float* __restrict__ feat4,
                                              const float* __restrict__ er1,
                                              float* __restrict__ P) {
    __shared__ float sacc[CH1 * 4];          // 50000 B
    __shared__ unsigned squeue[16][QCAP];    // 8192 B
    int b = blockIdx.x, c = blockIdx.y, g = blockIdx.z;
    for (int i = threadIdx.x; i < CH1 * 4; i += 1024) sacc[i] = 0.f;
    __syncthreads();
    int base = c * CH1;
    const int* sp = src + (size_t)g * NE;
    const int* dp = dst + (size_t)g * NE;
    const float* f4 = feat4 + (size_t)g * NN * 4;
    const float* erp = er1 + (size_t)g * NN + base;
    int wid = threadIdx.x >> 6, lane = threadIdx.x & 63;
    unsigned* q = squeue[wid];
    unsigned long long lmask = (1ull << lane) - 1;
    int qn = 0;
    int e0 = b * SL1, eend = e0 + SL1;
    int iters = (SL1 + 1023) / 1024;
    for (int it = 0; it < iters; ++it) {
        int e = e0 + it * 1024 + (wid << 6) + lane;
        bool hit = false;
        unsigned pack = 0;
        if (e < eend) {
            unsigned rel = (unsigned)(dp[e] - base);
            if (rel < CH1) { hit = true; pack = (rel << 20) | (unsigned)e; }
        }
        unsigned long long m = __ballot(hit);
        int off = qn + __popcll(m & lmask);
        if (hit) q[off] = pack;
        qn += __popcll(m);
        if (qn >= 64) {
            unsigned p = q[lane];
            int ee = p & 0xFFFFF;
            int rel = p >> 20;
            int s = sp[ee];
            float4 F = *(const float4*)(f4 + (size_t)s * 4);
            float wv = __expf(lrelu(F.w + erp[rel], 0.2f));
            atomicAdd(&sacc[rel * 4 + 0], wv * F.x);
            atomicAdd(&sacc[rel * 4 + 1], wv * F.y);
            atomicAdd(&sacc[rel * 4 + 2], wv * F.z);
            atomicAdd(&sacc[rel * 4 + 3], wv);
            qn -= 64;
            if (lane < qn) q[lane] = q[64 + lane];
        }
    }
    if (lane < qn) {
        unsigned p = q[lane];
        int ee = p & 0xFFFFF;
        int rel = p >> 20;
        int s = sp[ee];
        float4 F = *(const float4*)(f4 + (size_t)s * 4);
        float wv = __expf(lrelu(F.w + erp[rel], 0.2f));
        atomicAdd(&sacc[rel * 4 + 0], wv * F.x);
        atomicAdd(&sacc[rel * 4 + 1], wv * F.y);
        atomicAdd(&sacc[rel * 4 + 2], wv * F.z);
        atomicAdd(&sacc[rel * 4 + 3], wv);
    }
    __syncthreads();
    float* Pb = P + ((size_t)(g * C1 + c) * NB1 + b) * (CH1 * 4);
    for (int i = threadIdx.x; i < CH1 * 4; i += 1024) Pb[i] = sacc[i];
}

// den2 via LDS chunks + compaction (dst-chunked): sden[rel] += exp(lrelu(el2[s]+er2[d]))
__global__ __launch_bounds__(1024) void k_e2c(const int* __restrict__ src,
                                              const int* __restrict__ dst,
                                              const float* __restrict__ el2,
                                              const float* __restrict__ er2iv,
                                              float* __restrict__ P) {
    __shared__ float sden[CH2];              // 50000 B
    __shared__ unsigned squeue[16][QCAP];
    int b = blockIdx.x, c = blockIdx.y, g = blockIdx.z;
    for (int i = threadIdx.x; i < CH2; i += 1024) sden[i] = 0.f;
    __syncthreads();
    int base = c * CH2;
    const int* sp = src + (size_t)g * NE;
    const int* dp = dst + (size_t)g * NE;
    const float* el = el2 + (size_t)g * NN;
    const float* er = er2iv + (size_t)g * NN * 2;
    int wid = threadIdx.x >> 6, lane = threadIdx.x & 63;
    unsigned* q = squeue[wid];
    unsigned long long lmask = (1ull << lane) - 1;
    int qn = 0;
    int e0 = b * SL2, eend = e0 + SL2;
    int iters = (SL2 + 1023) / 1024;
    for (int it = 0; it < iters; ++it) {
        int e = e0 + it * 1024 + (wid << 6) + lane;
        bool hit = false;
        if (e < eend) hit = ((unsigned)(dp[e] - base) < CH2);
        unsigned long long m = __ballot(hit);
        int off = qn + __popcll(m & lmask);
        if (hit) q[off] = (unsigned)e;
        qn += __popcll(m);
        if (qn >= 64) {
            int ee = (int)q[lane];
            int d = dp[ee];
            float wv = __expf(lrelu(el[sp[ee]] + er[2 * d], 0.2f));
            atomicAdd(&sden[d - base], wv);
            qn -= 64;
            if (lane < qn) q[lane] = q[64 + lane];
        }
    }
    if (lane < qn) {
        int ee = (int)q[lane];
        int d = dp[ee];
        float wv = __expf(lrelu(el[sp[ee]] + er[2 * d], 0.2f));
        atomicAdd(&sden[d - base], wv);
    }
    __syncthreads();
    float* Pb = P + ((size_t)(g * C2 + c) * NB2 + b) * CH2;
    for (int i = threadIdx.x; i < CH2; i += 1024) Pb[i] = sden[i];
}

// q via LDS chunks + compaction (src-chunked): sq[rel] += exp(...) * invden2[d]
__global__ __launch_bounds__(1024) void k_e3c(const int* __restrict__ src,
                                              const int* __restrict__ dst,
                                              const float* __restrict__ el2,
                                              const float* __restrict__ er2iv,
                                              float* __restrict__ P) {
    __shared__ float sq[CH2];
    __shared__ unsigned squeue[16][QCAP];
    int b = blockIdx.x, c = blockIdx.y, g = blockIdx.z;
    for (int i = threadIdx.x; i < CH2; i += 1024) sq[i] = 0.f;
    __syncthreads();
    int base = c * CH2;
    const int* sp = src + (size_t)g * NE;
    const int* dp = dst + (size_t)g * NE;
    const float* el = el2 + (size_t)g * NN + base;
    const float* er = er2iv + (size_t)g * NN * 2;
    int wid = threadIdx.x >> 6, lane = threadIdx.x & 63;
    unsigned* q = squeue[wid];
    unsigned long long lmask = (1ull << lane) - 1;
    int qn = 0;
    int e0 = b * SL2, eend = e0 + SL2;
    int iters = (SL2 + 1023) / 1024;
    for (int it = 0; it < iters; ++it) {
        int e = e0 + it * 1024 + (wid << 6) + lane;
        bool hit = false;
        if (e < eend) hit = ((unsigned)(sp[e] - base) < CH2);
        unsigned long long m = __ballot(hit);
        int off = qn + __popcll(m & lmask);
        if (hit) q[off] = (unsigned)e;
        qn += __popcll(m);
        if (qn >= 64) {
            int ee = (int)q[lane];
            int rel = sp[ee] - base;
            float2 EI = *(const float2*)(er + 2 * dp[ee]);
            float wv = __expf(lrelu(el[rel] + EI.x, 0.2f));
            atomicAdd(&sq[rel], wv * EI.y);
            qn -= 64;
            if (lane < qn) q[lane] = q[64 + lane];
        }
    }
    if (lane < qn) {
        int ee = (int)q[lane];
        int rel = sp[ee] - base;
        float2 EI = *(const float2*)(er + 2 * dp[ee]);
        float wv = __expf(lrelu(el[rel] + EI.x, 0.2f));
        atomicAdd(&sq[rel], wv * EI.y);
    }
    __syncthreads();
    float* Pb = P + ((size_t)(g * C2 + c) * NB2 + b) * CH2;
    for (int i = threadIdx.x; i < CH2; i += 1024) Pb[i] = sq[i];
}

// Generic partial reduce: sums NB partials; writes out[idx*ostride+ooff] (optionally 1/s).
__global__ void k_red(const float* __restrict__ P, float* __restrict__ out,
                      int C, int NB, int CHW, int inv, int ostride, int ooff) {
    int T = 2 * C * CHW;
    int idx = blockIdx.x * blockDim.x + threadIdx.x;
    if (idx >= T) return;
    int gc = idx / CHW;
    int j = idx - gc * CHW;
    const float* Pp = P + ((size_t)gc * NB) * CHW + j;
    float s = 0.f;
    for (int b = 0; b < NB; ++b) s += Pp[(size_t)b * CHW];
    out[(size_t)idx * ostride + ooff] = inv ? (s != 0.f ? 1.f / s : 0.f) : s;
}

// Per node: g1 = relu(facc.xyz/facc.w @ W1h0 + b1); el2 = g1.u, er2iv[2n] = g1.v
__global__ void k_n1(const float* __restrict__ facc4, const float* __restrict__ W1,
                     const float* __restrict__ b1, const float* __restrict__ prep,
                     float* __restrict__ el2, float* __restrict__ er2iv) {
    __shared__ float sW[240], sB[80], sU[80], sV[80];
    for (int t = threadIdx.x; t < 80; t += blockDim.x) {
        sW[t] = W1[t];
        sW[80 + t] = W1[160 + t];
        sW[160 + t] = W1[320 + t];
        sB[t] = b1[t];
        sU[t] = prep[t];
        sV[t] = prep[80 + t];
    }
    __syncthreads();
    int g = blockIdx.y;
    int n = blockIdx.x * blockDim.x + threadIdx.x;
    if (n >= NN) return;
    float4 fa = *(const float4*)(facc4 + ((size_t)g * NN + n) * 4);
    float inv = fa.w != 0.f ? 1.f / fa.w : 0.f;
    float c0 = fa.x * inv, c1 = fa.y * inv, c2 = fa.z * inv;
    float el = 0.f, er = 0.f;
    #pragma unroll
    for (int f = 0; f < 80; ++f) {
        float gg = c0 * sW[f] + c1 * sW[80 + f] + c2 * sW[160 + f] + sB[f];
        gg = gg > 0.f ? gg : 0.f;
        el += gg * sU[f];
        er += gg * sV[f];
    }
    el2[g * NN + n] = el;
    er2iv[((size_t)g * NN + n) * 2] = er;
}

// A[g][0..79] = sum_n q[n] * g1[n]  — register accumulation over 128-node LDS tiles.
#define RT 128
__global__ void k_r(const float* __restrict__ facc4, const float* __restrict__ W1,
                    const float* __restrict__ b1, const float* __restrict__ q,
                    float* __restrict__ A) {
    __shared__ float4 sF[RT];
    __shared__ float sQ[RT];
    __shared__ float sW[240], sB[80];
    __shared__ float sA[240];
    int t = threadIdx.x;
    for (int i = t; i < 80; i += 256) {
        sW[i] = W1[i];
        sW[80 + i] = W1[160 + i];
        sW[160 + i] = W1[320 + i];
        sB[i] = b1[i];
    }
    int g = blockIdx.y;
    int grp = t / 80, f = t - grp * 80;
    float acc = 0.f;
    for (int n0 = blockIdx.x * RT; n0 < NN; n0 += gridDim.x * RT) {
        __syncthreads();
        if (t < RT) {
            int n = n0 + t;
            sF[t] = (n < NN) ? *(const float4*)(facc4 + ((size_t)g * NN + n) * 4)
                             : make_float4(0.f, 0.f, 0.f, 0.f);
        } else if (t < 2 * RT) {
            int n = n0 + t - RT;
            sQ[t - RT] = (n < NN) ? q[g * NN + n] : 0.f;
        }
        __syncthreads();
        if (grp < 3) {
            for (int i = grp; i < RT; i += 3) {
                float qn = sQ[i];
                if (qn == 0.f) continue;
                float4 fa = sF[i];
                float inv = fa.w != 0.f ? 1.f / fa.w : 0.f;
                float c0 = fa.x * inv, c1 = fa.y * inv, c2 = fa.z * inv;
                float gg = c0 * sW[f] + c1 * sW[80 + f] + c2 * sW[160 + f] + sB[f];
                gg = gg > 0.f ? gg : 0.f;
                acc += qn * gg;
            }
        }
    }
    if (grp < 3) sA[t] = acc;
    __syncthreads();
    if (t < 80) atomicAdd(&A[g * 80 + t], sA[t] + sA[80 + t] + sA[160 + t]);
}

// Image matmul: emb_acc[g][k] += x[g] @ W_lin1[:,k], 64 blocks each owning 64 rows.
__global__ void k_img1(const float* __restrict__ x, const float* __restrict__ W1,
                       float* __restrict__ emb_acc) {
    __shared__ float part[8][64];
    int t = threadIdx.x;  // 256
    int kk = t & 31, rq = t >> 5;
    int r0 = blockIdx.x * 64;
    float a0 = 0.f, a1 = 0.f;
    if (kk < 30) {
        for (int i = 0; i < 8; ++i) {
            int r = r0 + rq * 8 + i;
            float wv = W1[r * 30 + kk];
            a0 += x[r] * wv;
            a1 += x[4096 + r] * wv;
        }
    }
    part[rq][kk] = a0;
    part[rq][32 + kk] = a1;
    __syncthreads();
    if (t < 60) {
        int g = t / 30, k = t - g * 30;
        float s = 0.f;
        #pragma unroll
        for (int rr = 0; rr < 8; ++rr) s += part[rr][g * 32 + k];
        atomicAdd(&emb_acc[g * 30 + k], s);
    }
}

// Image conv tail: h = lrelu(Wc1@emb); h2 = lrelu(Wc2@h) [30]
__global__ void k_img2(const float* __restrict__ emb_acc, const float* __restrict__ Wc1,
                       const float* __restrict__ Wc2, float* __restrict__ h2out) {
    __shared__ float emb[60];
    __shared__ float hh[80 * 30];
    int t = threadIdx.x;  // 256
    if (t < 60) emb[t] = emb_acc[t];
    __syncthreads();
    for (int p = t; p < 2400; p += 256) {
        int i = p / 30, j = p % 30;
        float v = Wc1[i * 2 + 0] * emb[j] + Wc1[i * 2 + 1] * emb[30 + j];
        hh[p] = lrelu(v, 0.01f);
    }
    __syncthreads();
    if (t < 30) {
        float acc = 0.f;
        for (int i = 0; i < 80; ++i) acc += Wc2[i] * hh[i * 30 + t];
        h2out[t] = lrelu(acc, 0.01f);
    }
}

// Final head
__global__ void k_final(const float* __restrict__ A, const float* __restrict__ W2g,
                        const float* __restrict__ b2, const float* __restrict__ Wg1,
                        const float* __restrict__ bg1, const float* __restrict__ h2,
                        const float* __restrict__ vocab, const float* __restrict__ W2f,
                        const float* __restrict__ W3, float* __restrict__ out, int out_size) {
    __shared__ float a[60];
    __shared__ float hc[70];
    __shared__ float tt[80];
    __shared__ float lp[2];
    int t = threadIdx.x;  // 128
    if (t < 60) {
        int i = t / 30, j = t % 30;
        float acc = 0.f;
        for (int f = 0; f < 80; ++f) acc += A[i * 80 + f] * W2g[f * 60 + j];
        a[t] = acc * (1.f / NN) + b2[j];
    }
    __syncthreads();
    if (t < 30) {
        float acc = bg1[t];
        for (int j = 0; j < 60; ++j) acc += a[j] * Wg1[j * 30 + t];
        hc[t] = acc;
        hc[30 + t] = h2[t];
        if (t < 10) hc[60 + t] = vocab[t];
    }
    __syncthreads();
    if (t < 80) {
        float acc = 0.f;
        for (int qd = 0; qd < 70; ++qd) acc += hc[qd] * W2f[qd * 80 + t];
        tt[t] = acc;
    }
    __syncthreads();
    if (t < 2) {
        float acc = 0.f;
        for (int p = 0; p < 80; ++p) acc += tt[p] * W3[p * 2 + t];
        lp[t] = acc;
    }
    __syncthreads();
    if (t == 0) {
        float m = fmaxf(lp[0], lp[1]);
        float lse = m + logf(expf(lp[0] - m) + expf(lp[1] - m));
        out[0] = lp[0] - lse;
        out[1] = lp[1] - lse;
    }
    for (int i = 2 + t; i < out_size; i += blockDim.x) out[i] = 0.f;
}

extern "C" void kernel_launch(void* const* d_in, const int* in_sizes, int n_in,
                              void* d_out, int out_size, void* d_ws, size_t ws_size,
                              hipStream_t stream) {
    const float* x        = (const float*)d_in[0];
    const float* vocab    = (const float*)d_in[1];
    const float* nodef    = (const float*)d_in[2];
    const int*   src      = (const int*)d_in[3];
    const int*   dst      = (const int*)d_in[4];
    const float* W_lin1   = (const float*)d_in[5];
    const float* Wc1      = (const float*)d_in[6];
    const float* Wc2      = (const float*)d_in[7];
    const float* gat1_W   = (const float*)d_in[8];
    const float* gat1_al  = (const float*)d_in[9];
    const float* gat1_ar  = (const float*)d_in[10];
    const float* gat1_b   = (const float*)d_in[11];
    const float* gat2_W   = (const float*)d_in[12];
    const float* gat2_al  = (const float*)d_in[13];
    const float* gat2_ar  = (const float*)d_in[14];
    const float* gat2_b   = (const float*)d_in[15];
    const float* Wg1      = (const float*)d_in[16];
    const float* bg1      = (const float*)d_in[17];
    const float* W2       = (const float*)d_in[18];
    const float* W3       = (const float*)d_in[19];
    (void)in_sizes; (void)n_in; (void)ws_size;

    float* w = (float*)d_ws;
    size_t off = 0;
    auto alloc = [&](size_t n) { size_t o = off; off += (n + 63) & ~(size_t)63; return o; };
    size_t o_emb  = alloc(64);   // zeroed
    size_t o_A    = alloc(192);  // zeroed (contiguous with o_emb)
    size_t o_h2   = alloc(32);
    size_t o_prep = alloc(192);
    size_t o_feat = alloc((size_t)2 * NN * 4);
    size_t o_er1  = alloc(2 * NN);
    size_t o_el2  = alloc(2 * NN);
    size_t o_eriv = alloc((size_t)2 * NN * 2);
    size_t o_facc = alloc((size_t)2 * NN * 4);
    size_t o_q    = alloc(2 * NN);
    size_t o_P    = alloc((size_t)2 * C1 * NB1 * CH1 * 4);

    hipMemsetAsync(w + o_emb, 0, 256 * sizeof(float), stream);
    k_prep<<<1, 128, 0, stream>>>(gat1_W, gat1_al, gat1_ar, gat2_W, gat2_al, gat2_ar, w + o_prep);
    k_img1<<<64, 256, 0, stream>>>(x, W_lin1, w + o_emb);
    k_img2<<<1, 256, 0, stream>>>(w + o_emb, Wc1, Wc2, w + o_h2);

    dim3 gN((NN + 255) / 256, 2);
    k_pack<<<gN, 256, 0, stream>>>(nodef, w + o_prep, w + o_feat, w + o_er1);

    k_e1c<<<dim3(NB1, C1, 2), 1024, 0, stream>>>(src, dst, w + o_feat, w + o_er1, w + o_P);
    k_red<<<(2 * NN * 4 + 1023) / 1024, 1024, 0, stream>>>(w + o_P, w + o_facc,
                                                           C1, NB1, CH1 * 4, 0, 1, 0);
    k_n1<<<gN, 256, 0, stream>>>(w + o_facc, gat1_W, gat1_b, w + o_prep,
                                 w + o_el2, w + o_eriv);

    k_e2c<<<dim3(NB2, C2, 2), 1024, 0, stream>>>(src, dst, w + o_el2, w + o_eriv, w + o_P);
    k_red<<<(2 * NN + 1023) / 1024, 1024, 0, stream>>>(w + o_P, w + o_eriv,
                                                       C2, NB2, CH2, 1, 2, 1);

    k_e3c<<<dim3(NB2, C2, 2), 1024, 0, stream>>>(src, dst, w + o_el2, w + o_eriv, w + o_P);
    k_red<<<(2 * NN + 1023) / 1024, 1024, 0, stream>>>(w + o_P, w + o_q,
                                                       C2, NB2, CH2, 0, 1, 0);

    k_r<<<dim3(128, 2), 256, 0, stream>>>(w + o_facc, gat1_W, gat1_b, w + o_q, w + o_A);
    k_final<<<1, 128, 0, stream>>>(w + o_A, gat2_W, gat2_b, Wg1, bg1, w + o_h2, vocab,
                                   W2, W3, (float*)d_out, out_size);
}

// Round 9
// 184.397 us; speedup vs baseline: 6.1742x; 1.0903x over previous
//
#include <hip/hip_runtime.h>
#include <math.h>

#define NN 50000
#define NE 800000

// e1 chunking (facc4: 4 floats/node)
#define CH1 3125            // nodes/chunk -> 50 KB LDS
#define C1  16
#define NB1 16
#define SL1 (NE / NB1)      // 50000
// e2/e3 chunking (scalar/node)
#define CH2 12500           // 50 KB LDS
#define C2  4
#define NB2 32
#define SL2 (NE / NB2)      // 25000
#define QCAP 128            // per-wave compaction queue

__device__ __forceinline__ float lrelu(float x, float s) { return x >= 0.f ? x : s * x; }

// prep[0..79]=u (W2h0@al2), prep[80..159]=v (W2h0@ar2), prep[160..162]=wl1, prep[163..165]=wr1
__global__ void k_prep(const float* __restrict__ W1, const float* __restrict__ al1,
                       const float* __restrict__ ar1, const float* __restrict__ W2,
                       const float* __restrict__ al2, const float* __restrict__ ar2,
                       float* __restrict__ prep) {
    int t = threadIdx.x;  // 128
    if (t < 80) {
        float u = 0.f, v = 0.f;
        for (int j = 0; j < 30; ++j) {
            float w = W2[t * 60 + j];  // head0 cols of [80, 60]
            u += w * al2[j];
            v += w * ar2[j];
        }
        prep[t] = u;
        prep[80 + t] = v;
    } else if (t < 83) {
        int c = t - 80;
        float a = 0.f, b = 0.f;
        for (int f = 0; f < 80; ++f) {
            float w = W1[c * 160 + f];  // head0 cols of [3, 160]
            a += w * al1[f];
            b += w * ar1[f];
        }
        prep[160 + c] = a;
        prep[163 + c] = b;
    }
}

// Per node: feat4 = {f0, f1, f2, el1}; er1 = f.wr1
__global__ void k_pack(const float* __restrict__ nodef, const float* __restrict__ prep,
                       float* __restrict__ feat4, float* __restrict__ er1) {
    int g = blockIdx.y;
    int n = blockIdx.x * blockDim.x + threadIdx.x;
    if (n >= NN) return;
    const float* f = nodef + ((size_t)g * NN + n) * 3;
    float f0 = f[0], f1 = f[1], f2 = f[2];
    *(float4*)(feat4 + ((size_t)g * NN + n) * 4) =
        make_float4(f0, f1, f2, f0 * prep[160] + f1 * prep[161] + f2 * prep[162]);
    er1[g * NN + n] = f0 * prep[163] + f1 * prep[164] + f2 * prep[165];
}

// GAT1 sufficient stats: int4-batched scan + wave ballot-compaction queue.
__global__ __launch_bounds__(1024) void k_e1c(const int* __restrict__ src,
                                              const int* __restrict__ dst,
                                              const float* __restrict__ feat4,
                                              const float* __restrict__ er1,
                                              float* __restrict__ P) {
    __shared__ float sacc[CH1 * 4];          // 50000 B
    __shared__ unsigned squeue[16][QCAP];    // 8192 B
    int b = blockIdx.x, c = blockIdx.y, g = blockIdx.z;
    for (int i = threadIdx.x; i < CH1 * 4; i += 1024) sacc[i] = 0.f;
    __syncthreads();
    int base = c * CH1;
    const int* sp = src + (size_t)g * NE;
    const int* dp = dst + (size_t)g * NE;
    const float* f4 = feat4 + (size_t)g * NN * 4;
    const float* erp = er1 + (size_t)g * NN + base;
    int wid = threadIdx.x >> 6, lane = threadIdx.x & 63;
    unsigned* q = squeue[wid];
    unsigned long long lmask = (1ull << lane) - 1;
    int qn = 0;
    int e0 = b * SL1, eend = e0 + SL1;
    int iters = (SL1 + 4095) / 4096;
    for (int it = 0; it < iters; ++it) {
        int ebase = e0 + it * 4096 + (wid << 8) + (lane << 2);
        int4 dv = make_int4(-1, -1, -1, -1);
        if (ebase < eend) dv = *(const int4*)(dp + ebase);  // 4 edges, one dwordx4
        #pragma unroll
        for (int j = 0; j < 4; ++j) {
            int dj = (j == 0) ? dv.x : (j == 1) ? dv.y : (j == 2) ? dv.z : dv.w;
            unsigned rel = (unsigned)(dj - base);
            bool hit = rel < CH1;
            unsigned long long m = __ballot(hit);
            if (hit) q[qn + __popcll(m & lmask)] = (rel << 20) | (unsigned)(ebase + j);
            qn += __popcll(m);
            if (qn >= 64) {
                unsigned p = q[lane];
                int ee = p & 0xFFFFF;
                int r = p >> 20;
                int s = sp[ee];
                float4 F = *(const float4*)(f4 + (size_t)s * 4);
                float wv = __expf(lrelu(F.w + erp[r], 0.2f));
                atomicAdd(&sacc[r * 4 + 0], wv * F.x);
                atomicAdd(&sacc[r * 4 + 1], wv * F.y);
                atomicAdd(&sacc[r * 4 + 2], wv * F.z);
                atomicAdd(&sacc[r * 4 + 3], wv);
                qn -= 64;
                if (lane < qn) q[lane] = q[64 + lane];
            }
        }
    }
    if (lane < qn) {
        unsigned p = q[lane];
        int ee = p & 0xFFFFF;
        int r = p >> 20;
        int s = sp[ee];
        float4 F = *(const float4*)(f4 + (size_t)s * 4);
        float wv = __expf(lrelu(F.w + erp[r], 0.2f));
        atomicAdd(&sacc[r * 4 + 0], wv * F.x);
        atomicAdd(&sacc[r * 4 + 1], wv * F.y);
        atomicAdd(&sacc[r * 4 + 2], wv * F.z);
        atomicAdd(&sacc[r * 4 + 3], wv);
    }
    __syncthreads();
    float* Pb = P + ((size_t)(g * C1 + c) * NB1 + b) * (CH1 * 4);
    for (int i = threadIdx.x; i < CH1 * 4; i += 1024) Pb[i] = sacc[i];
}

// den2: int4-batched scan + compaction (dst-chunked)
__global__ __launch_bounds__(1024) void k_e2c(const int* __restrict__ src,
                                              const int* __restrict__ dst,
                                              const float* __restrict__ el2,
                                              const float* __restrict__ er2iv,
                                              float* __restrict__ P) {
    __shared__ float sden[CH2];              // 50000 B
    __shared__ unsigned squeue[16][QCAP];
    int b = blockIdx.x, c = blockIdx.y, g = blockIdx.z;
    for (int i = threadIdx.x; i < CH2; i += 1024) sden[i] = 0.f;
    __syncthreads();
    int base = c * CH2;
    const int* sp = src + (size_t)g * NE;
    const int* dp = dst + (size_t)g * NE;
    const float* el = el2 + (size_t)g * NN;
    const float* er = er2iv + (size_t)g * NN * 2;
    int wid = threadIdx.x >> 6, lane = threadIdx.x & 63;
    unsigned* q = squeue[wid];
    unsigned long long lmask = (1ull << lane) - 1;
    int qn = 0;
    int e0 = b * SL2, eend = e0 + SL2;
    int iters = (SL2 + 4095) / 4096;
    for (int it = 0; it < iters; ++it) {
        int ebase = e0 + it * 4096 + (wid << 8) + (lane << 2);
        int4 dv = make_int4(-1, -1, -1, -1);
        if (ebase < eend) dv = *(const int4*)(dp + ebase);
        #pragma unroll
        for (int j = 0; j < 4; ++j) {
            int dj = (j == 0) ? dv.x : (j == 1) ? dv.y : (j == 2) ? dv.z : dv.w;
            bool hit = (unsigned)(dj - base) < CH2;
            unsigned long long m = __ballot(hit);
            if (hit) q[qn + __popcll(m & lmask)] = (unsigned)(ebase + j);
            qn += __popcll(m);
            if (qn >= 64) {
                int ee = (int)q[lane];
                int d = dp[ee];
                float wv = __expf(lrelu(el[sp[ee]] + er[2 * d], 0.2f));
                atomicAdd(&sden[d - base], wv);
                qn -= 64;
                if (lane < qn) q[lane] = q[64 + lane];
            }
        }
    }
    if (lane < qn) {
        int ee = (int)q[lane];
        int d = dp[ee];
        float wv = __expf(lrelu(el[sp[ee]] + er[2 * d], 0.2f));
        atomicAdd(&sden[d - base], wv);
    }
    __syncthreads();
    float* Pb = P + ((size_t)(g * C2 + c) * NB2 + b) * CH2;
    for (int i = threadIdx.x; i < CH2; i += 1024) Pb[i] = sden[i];
}

// q: int4-batched scan + compaction (src-chunked): sq[rel] += exp(...) * invden2[d]
__global__ __launch_bounds__(1024) void k_e3c(const int* __restrict__ src,
                                              const int* __restrict__ dst,
                                              const float* __restrict__ el2,
                                              const float* __restrict__ er2iv,
                                              float* __restrict__ P) {
    __shared__ float sq[CH2];
    __shared__ unsigned squeue[16][QCAP];
    int b = blockIdx.x, c = blockIdx.y, g = blockIdx.z;
    for (int i = threadIdx.x; i < CH2; i += 1024) sq[i] = 0.f;
    __syncthreads();
    int base = c * CH2;
    const int* sp = src + (size_t)g * NE;
    const int* dp = dst + (size_t)g * NE;
    const float* el = el2 + (size_t)g * NN + base;
    const float* er = er2iv + (size_t)g * NN * 2;
    int wid = threadIdx.x >> 6, lane = threadIdx.x & 63;
    unsigned* q = squeue[wid];
    unsigned long long lmask = (1ull << lane) - 1;
    int qn = 0;
    int e0 = b * SL2, eend = e0 + SL2;
    int iters = (SL2 + 4095) / 4096;
    for (int it = 0; it < iters; ++it) {
        int ebase = e0 + it * 4096 + (wid << 8) + (lane << 2);
        int4 sv = make_int4(-1, -1, -1, -1);
        if (ebase < eend) sv = *(const int4*)(sp + ebase);
        #pragma unroll
        for (int j = 0; j < 4; ++j) {
            int sj = (j == 0) ? sv.x : (j == 1) ? sv.y : (j == 2) ? sv.z : sv.w;
            bool hit = (unsigned)(sj - base) < CH2;
            unsigned long long m = __ballot(hit);
            if (hit) q[qn + __popcll(m & lmask)] = (unsigned)(ebase + j);
            qn += __popcll(m);
            if (qn >= 64) {
                int ee = (int)q[lane];
                int rel = sp[ee] - base;
                float2 EI = *(const float2*)(er + 2 * dp[ee]);
                float wv = __expf(lrelu(el[rel] + EI.x, 0.2f));
                atomicAdd(&sq[rel], wv * EI.y);
                qn -= 64;
                if (lane < qn) q[lane] = q[64 + lane];
            }
        }
    }
    if (lane < qn) {
        int ee = (int)q[lane];
        int rel = sp[ee] - base;
        float2 EI = *(const float2*)(er + 2 * dp[ee]);
        float wv = __expf(lrelu(el[rel] + EI.x, 0.2f));
        atomicAdd(&sq[rel], wv * EI.y);
    }
    __syncthreads();
    float* Pb = P + ((size_t)(g * C2 + c) * NB2 + b) * CH2;
    for (int i = threadIdx.x; i < CH2; i += 1024) Pb[i] = sq[i];
}

// Generic partial reduce: sums NB partials; writes out[idx*ostride+ooff] (optionally 1/s).
__global__ void k_red(const float* __restrict__ P, float* __restrict__ out,
                      int C, int NB, int CHW, int inv, int ostride, int ooff) {
    int T = 2 * C * CHW;
    int idx = blockIdx.x * blockDim.x + threadIdx.x;
    if (idx >= T) return;
    int gc = idx / CHW;
    int j = idx - gc * CHW;
    const float* Pp = P + ((size_t)gc * NB) * CHW + j;
    float s = 0.f;
    for (int b = 0; b < NB; ++b) s += Pp[(size_t)b * CHW];
    out[(size_t)idx * ostride + ooff] = inv ? (s != 0.f ? 1.f / s : 0.f) : s;
}

// Per node: g1 = relu(facc.xyz/facc.w @ W1h0 + b1); el2 = g1.u, er2iv[2n] = g1.v
__global__ void k_n1(const float* __restrict__ facc4, const float* __restrict__ W1,
                     const float* __restrict__ b1, const float* __restrict__ prep,
                     float* __restrict__ el2, float* __restrict__ er2iv) {
    __shared__ float sW[240], sB[80], sU[80], sV[80];
    for (int t = threadIdx.x; t < 80; t += blockDim.x) {
        sW[t] = W1[t];
        sW[80 + t] = W1[160 + t];
        sW[160 + t] = W1[320 + t];
        sB[t] = b1[t];
        sU[t] = prep[t];
        sV[t] = prep[80 + t];
    }
    __syncthreads();
    int g = blockIdx.y;
    int n = blockIdx.x * blockDim.x + threadIdx.x;
    if (n >= NN) return;
    float4 fa = *(const float4*)(facc4 + ((size_t)g * NN + n) * 4);
    float inv = fa.w != 0.f ? 1.f / fa.w : 0.f;
    float c0 = fa.x * inv, c1 = fa.y * inv, c2 = fa.z * inv;
    float el = 0.f, er = 0.f;
    #pragma unroll
    for (int f = 0; f < 80; ++f) {
        float gg = c0 * sW[f] + c1 * sW[80 + f] + c2 * sW[160 + f] + sB[f];
        gg = gg > 0.f ? gg : 0.f;
        el += gg * sU[f];
        er += gg * sV[f];
    }
    el2[g * NN + n] = el;
    er2iv[((size_t)g * NN + n) * 2] = er;
}

// A[g][0..79] = sum_n q[n] * g1[n]  — register accumulation over 128-node LDS tiles.
#define RT 128
__global__ void k_r(const float* __restrict__ facc4, const float* __restrict__ W1,
                    const float* __restrict__ b1, const float* __restrict__ q,
                    float* __restrict__ A) {
    __shared__ float4 sF[RT];
    __shared__ float sQ[RT];
    __shared__ float sW[240], sB[80];
    __shared__ float sA[240];
    int t = threadIdx.x;
    for (int i = t; i < 80; i += 256) {
        sW[i] = W1[i];
        sW[80 + i] = W1[160 + i];
        sW[160 + i] = W1[320 + i];
        sB[i] = b1[i];
    }
    int g = blockIdx.y;
    int grp = t / 80, f = t - grp * 80;
    float acc = 0.f;
    for (int n0 = blockIdx.x * RT; n0 < NN; n0 += gridDim.x * RT) {
        __syncthreads();
        if (t < RT) {
            int n = n0 + t;
            sF[t] = (n < NN) ? *(const float4*)(facc4 + ((size_t)g * NN + n) * 4)
                             : make_float4(0.f, 0.f, 0.f, 0.f);
        } else if (t < 2 * RT) {
            int n = n0 + t - RT;
            sQ[t - RT] = (n < NN) ? q[g * NN + n] : 0.f;
        }
        __syncthreads();
        if (grp < 3) {
            for (int i = grp; i < RT; i += 3) {
                float qn = sQ[i];
                if (qn == 0.f) continue;
                float4 fa = sF[i];
                float inv = fa.w != 0.f ? 1.f / fa.w : 0.f;
                float c0 = fa.x * inv, c1 = fa.y * inv, c2 = fa.z * inv;
                float gg = c0 * sW[f] + c1 * sW[80 + f] + c2 * sW[160 + f] + sB[f];
                gg = gg > 0.f ? gg : 0.f;
                acc += qn * gg;
            }
        }
    }
    if (grp < 3) sA[t] = acc;
    __syncthreads();
    if (t < 80) atomicAdd(&A[g * 80 + t], sA[t] + sA[80 + t] + sA[160 + t]);
}

// Image matmul: emb_acc[g][k] += x[g] @ W_lin1[:,k], 64 blocks each owning 64 rows.
__global__ void k_img1(const float* __restrict__ x, const float* __restrict__ W1,
                       float* __restrict__ emb_acc) {
    __shared__ float part[8][64];
    int t = threadIdx.x;  // 256
    int kk = t & 31, rq = t >> 5;
    int r0 = blockIdx.x * 64;
    float a0 = 0.f, a1 = 0.f;
    if (kk < 30) {
        for (int i = 0; i < 8; ++i) {
            int r = r0 + rq * 8 + i;
            float wv = W1[r * 30 + kk];
            a0 += x[r] * wv;
            a1 += x[4096 + r] * wv;
        }
    }
    part[rq][kk] = a0;
    part[rq][32 + kk] = a1;
    __syncthreads();
    if (t < 60) {
        int g = t / 30, k = t - g * 30;
        float s = 0.f;
        #pragma unroll
        for (int rr = 0; rr < 8; ++rr) s += part[rr][g * 32 + k];
        atomicAdd(&emb_acc[g * 30 + k], s);
    }
}

// Image conv tail: h = lrelu(Wc1@emb); h2 = lrelu(Wc2@h) [30]
__global__ void k_img2(const float* __restrict__ emb_acc, const float* __restrict__ Wc1,
                       const float* __restrict__ Wc2, float* __restrict__ h2out) {
    __shared__ float emb[60];
    __shared__ float hh[80 * 30];
    int t = threadIdx.x;  // 256
    if (t < 60) emb[t] = emb_acc[t];
    __syncthreads();
    for (int p = t; p < 2400; p += 256) {
        int i = p / 30, j = p % 30;
        float v = Wc1[i * 2 + 0] * emb[j] + Wc1[i * 2 + 1] * emb[30 + j];
        hh[p] = lrelu(v, 0.01f);
    }
    __syncthreads();
    if (t < 30) {
        float acc = 0.f;
        for (int i = 0; i < 80; ++i) acc += Wc2[i] * hh[i * 30 + t];
        h2out[t] = lrelu(acc, 0.01f);
    }
}

// Final head
__global__ void k_final(const float* __restrict__ A, const float* __restrict__ W2g,
                        const float* __restrict__ b2, const float* __restrict__ Wg1,
                        const float* __restrict__ bg1, const float* __restrict__ h2,
                        const float* __restrict__ vocab, const float* __restrict__ W2f,
                        const float* __restrict__ W3, float* __restrict__ out, int out_size) {
    __shared__ float a[60];
    __shared__ float hc[70];
    __shared__ float tt[80];
    __shared__ float lp[2];
    int t = threadIdx.x;  // 128
    if (t < 60) {
        int i = t / 30, j = t % 30;
        float acc = 0.f;
        for (int f = 0; f < 80; ++f) acc += A[i * 80 + f] * W2g[f * 60 + j];
        a[t] = acc * (1.f / NN) + b2[j];
    }
    __syncthreads();
    if (t < 30) {
        float acc = bg1[t];
        for (int j = 0; j < 60; ++j) acc += a[j] * Wg1[j * 30 + t];
        hc[t] = acc;
        hc[30 + t] = h2[t];
        if (t < 10) hc[60 + t] = vocab[t];
    }
    __syncthreads();
    if (t < 80) {
        float acc = 0.f;
        for (int qd = 0; qd < 70; ++qd) acc += hc[qd] * W2f[qd * 80 + t];
        tt[t] = acc;
    }
    __syncthreads();
    if (t < 2) {
        float acc = 0.f;
        for (int p = 0; p < 80; ++p) acc += tt[p] * W3[p * 2 + t];
        lp[t] = acc;
    }
    __syncthreads();
    if (t == 0) {
        float m = fmaxf(lp[0], lp[1]);
        float lse = m + logf(expf(lp[0] - m) + expf(lp[1] - m));
        out[0] = lp[0] - lse;
        out[1] = lp[1] - lse;
    }
    for (int i = 2 + t; i < out_size; i += blockDim.x) out[i] = 0.f;
}

extern "C" void kernel_launch(void* const* d_in, const int* in_sizes, int n_in,
                              void* d_out, int out_size, void* d_ws, size_t ws_size,
                              hipStream_t stream) {
    const float* x        = (const float*)d_in[0];
    const float* vocab    = (const float*)d_in[1];
    const float* nodef    = (const float*)d_in[2];
    const int*   src      = (const int*)d_in[3];
    const int*   dst      = (const int*)d_in[4];
    const float* W_lin1   = (const float*)d_in[5];
    const float* Wc1      = (const float*)d_in[6];
    const float* Wc2      = (const float*)d_in[7];
    const float* gat1_W   = (const float*)d_in[8];
    const float* gat1_al  = (const float*)d_in[9];
    const float* gat1_ar  = (const float*)d_in[10];
    const float* gat1_b   = (const float*)d_in[11];
    const float* gat2_W   = (const float*)d_in[12];
    const float* gat2_al  = (const float*)d_in[13];
    const float* gat2_ar  = (const float*)d_in[14];
    const float* gat2_b   = (const float*)d_in[15];
    const float* Wg1      = (const float*)d_in[16];
    const float* bg1      = (const float*)d_in[17];
    const float* W2       = (const float*)d_in[18];
    const float* W3       = (const float*)d_in[19];
    (void)in_sizes; (void)n_in; (void)ws_size;

    float* w = (float*)d_ws;
    size_t off = 0;
    auto alloc = [&](size_t n) { size_t o = off; off += (n + 63) & ~(size_t)63; return o; };
    size_t o_emb  = alloc(64);   // zeroed
    size_t o_A    = alloc(192);  // zeroed (contiguous with o_emb)
    size_t o_h2   = alloc(32);
    size_t o_prep = alloc(192);
    size_t o_feat = alloc((size_t)2 * NN * 4);
    size_t o_er1  = alloc(2 * NN);
    size_t o_el2  = alloc(2 * NN);
    size_t o_eriv = alloc((size_t)2 * NN * 2);
    size_t o_facc = alloc((size_t)2 * NN * 4);
    size_t o_q    = alloc(2 * NN);
    size_t o_P    = alloc((size_t)2 * C1 * NB1 * CH1 * 4);  // 25.6 MB

    hipMemsetAsync(w + o_emb, 0, 256 * sizeof(float), stream);
    k_prep<<<1, 128, 0, stream>>>(gat1_W, gat1_al, gat1_ar, gat2_W, gat2_al, gat2_ar, w + o_prep);
    k_img1<<<64, 256, 0, stream>>>(x, W_lin1, w + o_emb);
    k_img2<<<1, 256, 0, stream>>>(w + o_emb, Wc1, Wc2, w + o_h2);

    dim3 gN((NN + 255) / 256, 2);
    k_pack<<<gN, 256, 0, stream>>>(nodef, w + o_prep, w + o_feat, w + o_er1);

    k_e1c<<<dim3(NB1, C1, 2), 1024, 0, stream>>>(src, dst, w + o_feat, w + o_er1, w + o_P);
    k_red<<<(2 * NN * 4 + 1023) / 1024, 1024, 0, stream>>>(w + o_P, w + o_facc,
                                                           C1, NB1, CH1 * 4, 0, 1, 0);
    k_n1<<<gN, 256, 0, stream>>>(w + o_facc, gat1_W, gat1_b, w + o_prep,
                                 w + o_el2, w + o_eriv);

    k_e2c<<<dim3(NB2, C2, 2), 1024, 0, stream>>>(src, dst, w + o_el2, w + o_eriv, w + o_P);
    k_red<<<(2 * NN + 1023) / 1024, 1024, 0, stream>>>(w + o_P, w + o_eriv,
                                                       C2, NB2, CH2, 1, 2, 1);

    k_e3c<<<dim3(NB2, C2, 2), 1024, 0, stream>>>(src, dst, w + o_el2, w + o_eriv, w + o_P);
    k_red<<<(2 * NN + 1023) / 1024, 1024, 0, stream>>>(w + o_P, w + o_q,
                                                       C2, NB2, CH2, 0, 1, 0);

    k_r<<<dim3(128, 2), 256, 0, stream>>>(w + o_facc, gat1_W, gat1_b, w + o_q, w + o_A);
    k_final<<<1, 128, 0, stream>>>(w + o_A, gat2_W, gat2_b, Wg1, bg1, w + o_h2, vocab,
                                   W2, W3, (float*)d_out, out_size);
}

// Round 10
// 176.059 us; speedup vs baseline: 6.4666x; 1.0474x over previous
//
#include <hip/hip_runtime.h>
#include <math.h>

#define NN 50000
#define NE 800000

// e1 chunking (facc4: 4 floats/node)
#define CH1 3125            // nodes/chunk -> 50 KB LDS
#define C1  16
#define NB1 16
#define SL1 (NE / NB1)      // 50000
// e2/e3 chunking (scalar/node)
#define CH2 12500           // 50 KB LDS
#define C2  4
#define NB2 32
#define SL2 (NE / NB2)      // 25000
#define QCAP 128

typedef unsigned short u16;

__device__ __forceinline__ float lrelu(float x, float s) { return x >= 0.f ? x : s * x; }

// Fused prologue. Blocks [0,64): image matmul. [64,456): per-node pack. [456,...): u16 cvt.
__global__ void k_pre(const float* __restrict__ x, const float* __restrict__ Wl,
                      const float* __restrict__ nodef,
                      const float* __restrict__ W1, const float* __restrict__ al1,
                      const float* __restrict__ ar1,
                      const int* __restrict__ src, const int* __restrict__ dst,
                      float* __restrict__ emb_acc, float* __restrict__ feat4,
                      float* __restrict__ er1, u16* __restrict__ src16,
                      u16* __restrict__ dst16) {
    int bid = blockIdx.x, t = threadIdx.x;
    if (bid < 64) {  // image matmul: emb_acc[g][k] += x[g][r0..r0+64] @ Wl
        __shared__ float part[8][64];
        int kk = t & 31, rq = t >> 5;
        int r0 = bid * 64;
        float a0 = 0.f, a1 = 0.f;
        if (kk < 30) {
            for (int i = 0; i < 8; ++i) {
                int r = r0 + rq * 8 + i;
                float wv = Wl[r * 30 + kk];
                a0 += x[r] * wv;
                a1 += x[4096 + r] * wv;
            }
        }
        part[rq][kk] = a0;
        part[rq][32 + kk] = a1;
        __syncthreads();
        if (t < 60) {
            int g = t / 30, k = t - g * 30;
            float s = 0.f;
            #pragma unroll
            for (int rr = 0; rr < 8; ++rr) s += part[rr][g * 32 + k];
            atomicAdd(&emb_acc[g * 30 + k], s);
        }
    } else if (bid < 456) {  // pack: feat4 = {f0,f1,f2, f.wl}; er1 = f.wr
        __shared__ float sP[6];  // wl[3], wr[3]
        if (t < 6) {
            int c = t >> 1;
            const float* av = (t & 1) ? ar1 : al1;  // head 0 rows
            float s = 0.f;
            for (int f = 0; f < 80; ++f) s += W1[c * 160 + f] * av[f];
            sP[(t & 1) * 3 + c] = s;
        }
        __syncthreads();
        int b2 = bid - 64;
        int g = b2 / 196;
        int n = (b2 - g * 196) * 256 + t;
        if (n < NN) {
            const float* f = nodef + ((size_t)g * NN + n) * 3;
            float f0 = f[0], f1 = f[1], f2 = f[2];
            *(float4*)(feat4 + ((size_t)g * NN + n) * 4) =
                make_float4(f0, f1, f2, f0 * sP[0] + f1 * sP[1] + f2 * sP[2]);
            er1[g * NN + n] = f0 * sP[3] + f1 * sP[4] + f2 * sP[5];
        }
    } else {  // cvt int32 -> u16, 8 per thread
        long flat = ((long)(bid - 456) * 256 + t) * 8;
        if (flat < 2L * 2 * NE) {
            int arr = flat >= 2L * NE;
            long rem = flat - (long)arr * 2 * NE;
            int g = rem >= NE;
            int e = (int)(rem - (long)g * NE);
            const int* ip = (arr ? dst : src) + (size_t)g * NE + e;
            int4 v0 = *(const int4*)ip;
            int4 v1 = *(const int4*)(ip + 4);
            uint4 o;
            o.x = (v0.x & 0xFFFF) | (v0.y << 16);
            o.y = (v0.z & 0xFFFF) | (v0.w << 16);
            o.z = (v1.x & 0xFFFF) | (v1.y << 16);
            o.w = (v1.z & 0xFFFF) | (v1.w << 16);
            *(uint4*)((arr ? dst16 : src16) + (size_t)g * NE + e) = o;
        }
    }
}

// GAT1 sufficient stats: ushort8-batched scan + wave ballot-compaction queue.
__global__ __launch_bounds__(1024) void k_e1c(const u16* __restrict__ src16,
                                              const u16* __restrict__ dst16,
                                              const float* __restrict__ feat4,
                                              const float* __restrict__ er1,
                                              float* __restrict__ P) {
    __shared__ float sacc[CH1 * 4];
    __shared__ unsigned squeue[16][QCAP];
    int b = blockIdx.x, c = blockIdx.y, g = blockIdx.z;
    for (int i = threadIdx.x; i < CH1 * 4; i += 1024) sacc[i] = 0.f;
    __syncthreads();
    unsigned base = c * CH1;
    const u16* sp = src16 + (size_t)g * NE;
    const u16* dp = dst16 + (size_t)g * NE;
    const float* f4 = feat4 + (size_t)g * NN * 4;
    const float* erp = er1 + (size_t)g * NN + base;
    int wid = threadIdx.x >> 6, lane = threadIdx.x & 63;
    unsigned* q = squeue[wid];
    unsigned long long lmask = (1ull << lane) - 1;
    int qn = 0;
    int e0 = b * SL1, eend = e0 + SL1;
    for (int it = 0; it < (SL1 + 8191) / 8192; ++it) {
        int ebase = e0 + it * 8192 + threadIdx.x * 8;
        uint4 dv = make_uint4(0xFFFFFFFFu, 0xFFFFFFFFu, 0xFFFFFFFFu, 0xFFFFFFFFu);
        if (ebase < eend) dv = *(const uint4*)(dp + ebase);  // 8 edges
        #pragma unroll
        for (int j = 0; j < 8; ++j) {
            unsigned word = (&dv.x)[j >> 1];
            unsigned dj = (j & 1) ? (word >> 16) : (word & 0xFFFF);
            unsigned rel = dj - base;
            bool hit = rel < CH1;
            unsigned long long m = __ballot(hit);
            if (hit) q[qn + __popcll(m & lmask)] = (rel << 20) | (unsigned)(ebase + j);
            qn += __popcll(m);
            if (qn >= 64) {
                unsigned p = q[lane];
                int ee = p & 0xFFFFF;
                int r = p >> 20;
                int s = sp[ee];
                float4 F = *(const float4*)(f4 + (size_t)s * 4);
                float wv = __expf(lrelu(F.w + erp[r], 0.2f));
                atomicAdd(&sacc[r * 4 + 0], wv * F.x);
                atomicAdd(&sacc[r * 4 + 1], wv * F.y);
                atomicAdd(&sacc[r * 4 + 2], wv * F.z);
                atomicAdd(&sacc[r * 4 + 3], wv);
                qn -= 64;
                if (lane < qn) q[lane] = q[64 + lane];
            }
        }
    }
    if (lane < qn) {
        unsigned p = q[lane];
        int ee = p & 0xFFFFF;
        int r = p >> 20;
        int s = sp[ee];
        float4 F = *(const float4*)(f4 + (size_t)s * 4);
        float wv = __expf(lrelu(F.w + erp[r], 0.2f));
        atomicAdd(&sacc[r * 4 + 0], wv * F.x);
        atomicAdd(&sacc[r * 4 + 1], wv * F.y);
        atomicAdd(&sacc[r * 4 + 2], wv * F.z);
        atomicAdd(&sacc[r * 4 + 3], wv);
    }
    __syncthreads();
    float* Pb = P + ((size_t)(g * C1 + c) * NB1 + b) * (CH1 * 4);
    for (int i = threadIdx.x; i < CH1 * 4; i += 1024) Pb[i] = sacc[i];
}

// den2: ushort8 scan + compaction (dst-chunked)
__global__ __launch_bounds__(1024) void k_e2c(const u16* __restrict__ src16,
                                              const u16* __restrict__ dst16,
                                              const float* __restrict__ el2,
                                              const float* __restrict__ er2iv,
                                              float* __restrict__ P) {
    __shared__ float sden[CH2];
    __shared__ unsigned squeue[16][QCAP];
    int b = blockIdx.x, c = blockIdx.y, g = blockIdx.z;
    for (int i = threadIdx.x; i < CH2; i += 1024) sden[i] = 0.f;
    __syncthreads();
    unsigned base = c * CH2;
    const u16* sp = src16 + (size_t)g * NE;
    const u16* dp = dst16 + (size_t)g * NE;
    const float* el = el2 + (size_t)g * NN;
    const float* er = er2iv + (size_t)g * NN * 2;
    int wid = threadIdx.x >> 6, lane = threadIdx.x & 63;
    unsigned* q = squeue[wid];
    unsigned long long lmask = (1ull << lane) - 1;
    int qn = 0;
    int e0 = b * SL2, eend = e0 + SL2;
    for (int it = 0; it < (SL2 + 8191) / 8192; ++it) {
        int ebase = e0 + it * 8192 + threadIdx.x * 8;
        uint4 dv = make_uint4(0xFFFFFFFFu, 0xFFFFFFFFu, 0xFFFFFFFFu, 0xFFFFFFFFu);
        if (ebase < eend) dv = *(const uint4*)(dp + ebase);
        #pragma unroll
        for (int j = 0; j < 8; ++j) {
            unsigned word = (&dv.x)[j >> 1];
            unsigned dj = (j & 1) ? (word >> 16) : (word & 0xFFFF);
            bool hit = (dj - base) < CH2;
            unsigned long long m = __ballot(hit);
            if (hit) q[qn + __popcll(m & lmask)] = (unsigned)(ebase + j);
            qn += __popcll(m);
            if (qn >= 64) {
                int ee = (int)q[lane];
                int d = dp[ee];
                float wv = __expf(lrelu(el[sp[ee]] + er[2 * d], 0.2f));
                atomicAdd(&sden[d - base], wv);
                qn -= 64;
                if (lane < qn) q[lane] = q[64 + lane];
            }
        }
    }
    if (lane < qn) {
        int ee = (int)q[lane];
        int d = dp[ee];
        float wv = __expf(lrelu(el[sp[ee]] + er[2 * d], 0.2f));
        atomicAdd(&sden[d - base], wv);
    }
    __syncthreads();
    float* Pb = P + ((size_t)(g * C2 + c) * NB2 + b) * CH2;
    for (int i = threadIdx.x; i < CH2; i += 1024) Pb[i] = sden[i];
}

// q: ushort8 scan + compaction (src-chunked): sq[rel] += exp(...) * invden2[d]
__global__ __launch_bounds__(1024) void k_e3c(const u16* __restrict__ src16,
                                              const u16* __restrict__ dst16,
                                              const float* __restrict__ el2,
                                              const float* __restrict__ er2iv,
                                              float* __restrict__ P) {
    __shared__ float sq[CH2];
    __shared__ unsigned squeue[16][QCAP];
    int b = blockIdx.x, c = blockIdx.y, g = blockIdx.z;
    for (int i = threadIdx.x; i < CH2; i += 1024) sq[i] = 0.f;
    __syncthreads();
    unsigned base = c * CH2;
    const u16* sp = src16 + (size_t)g * NE;
    const u16* dp = dst16 + (size_t)g * NE;
    const float* el = el2 + (size_t)g * NN + base;
    const float* er = er2iv + (size_t)g * NN * 2;
    int wid = threadIdx.x >> 6, lane = threadIdx.x & 63;
    unsigned* q = squeue[wid];
    unsigned long long lmask = (1ull << lane) - 1;
    int qn = 0;
    int e0 = b * SL2, eend = e0 + SL2;
    for (int it = 0; it < (SL2 + 8191) / 8192; ++it) {
        int ebase = e0 + it * 8192 + threadIdx.x * 8;
        uint4 sv = make_uint4(0xFFFFFFFFu, 0xFFFFFFFFu, 0xFFFFFFFFu, 0xFFFFFFFFu);
        if (ebase < eend) sv = *(const uint4*)(sp + ebase);
        #pragma unroll
        for (int j = 0; j < 8; ++j) {
            unsigned word = (&sv.x)[j >> 1];
            unsigned sj = (j & 1) ? (word >> 16) : (word & 0xFFFF);
            bool hit = (sj - base) < CH2;
            unsigned long long m = __ballot(hit);
            if (hit) q[qn + __popcll(m & lmask)] = (unsigned)(ebase + j);
            qn += __popcll(m);
            if (qn >= 64) {
                int ee = (int)q[lane];
                int rel = sp[ee] - base;
                float2 EI = *(const float2*)(er + 2 * dp[ee]);
                float wv = __expf(lrelu(el[rel] + EI.x, 0.2f));
                atomicAdd(&sq[rel], wv * EI.y);
                qn -= 64;
                if (lane < qn) q[lane] = q[64 + lane];
            }
        }
    }
    if (lane < qn) {
        int ee = (int)q[lane];
        int rel = sp[ee] - base;
        float2 EI = *(const float2*)(er + 2 * dp[ee]);
        float wv = __expf(lrelu(el[rel] + EI.x, 0.2f));
        atomicAdd(&sq[rel], wv * EI.y);
    }
    __syncthreads();
    float* Pb = P + ((size_t)(g * C2 + c) * NB2 + b) * CH2;
    for (int i = threadIdx.x; i < CH2; i += 1024) Pb[i] = sq[i];
}

// Generic partial reduce (den2 / q): out[idx*ostride+ooff] = (1/)sum_b P[...]
__global__ void k_red(const float* __restrict__ P, float* __restrict__ out,
                      int C, int NB, int CHW, int inv, int ostride, int ooff) {
    int T = 2 * C * CHW;
    int idx = blockIdx.x * blockDim.x + threadIdx.x;
    if (idx >= T) return;
    int gc = idx / CHW;
    int j = idx - gc * CHW;
    const float* Pp = P + ((size_t)gc * NB) * CHW + j;
    float s = 0.f;
    for (int b = 0; b < NB; ++b) s += Pp[(size_t)b * CHW];
    out[(size_t)idx * ostride + ooff] = inv ? (s != 0.f ? 1.f / s : 0.f) : s;
}

// Fused reduce(e1 partials) + node stage: facc4, el2, er2.
__global__ void k_n1r(const float* __restrict__ P, const float* __restrict__ W1,
                      const float* __restrict__ b1, const float* __restrict__ W2,
                      const float* __restrict__ al2, const float* __restrict__ ar2,
                      float* __restrict__ facc4, float* __restrict__ el2,
                      float* __restrict__ er2iv) {
    __shared__ float sW[240], sB[80], sU[80], sV[80];
    for (int t = threadIdx.x; t < 80; t += blockDim.x) {
        sW[t] = W1[t];
        sW[80 + t] = W1[160 + t];
        sW[160 + t] = W1[320 + t];
        sB[t] = b1[t];
        float u = 0.f, v = 0.f;
        for (int j = 0; j < 30; ++j) {
            float wv = W2[t * 60 + j];  // head0 cols of [80,60]
            u += wv * al2[j];
            v += wv * ar2[j];
        }
        sU[t] = u;
        sV[t] = v;
    }
    __syncthreads();
    int g = blockIdx.y;
    int n = blockIdx.x * blockDim.x + threadIdx.x;
    if (n >= NN) return;
    int c = n / CH1, rel = n - c * CH1;
    const float* Pp = P + ((size_t)(g * C1 + c) * NB1) * (CH1 * 4) + rel * 4;
    float4 fa = make_float4(0.f, 0.f, 0.f, 0.f);
    for (int b = 0; b < NB1; ++b) {
        float4 p = *(const float4*)(Pp + (size_t)b * (CH1 * 4));
        fa.x += p.x; fa.y += p.y; fa.z += p.z; fa.w += p.w;
    }
    *(float4*)(facc4 + ((size_t)g * NN + n) * 4) = fa;
    float inv = fa.w != 0.f ? 1.f / fa.w : 0.f;
    float c0 = fa.x * inv, c1 = fa.y * inv, c2 = fa.z * inv;
    float el = 0.f, er = 0.f;
    #pragma unroll
    for (int f = 0; f < 80; ++f) {
        float gg = c0 * sW[f] + c1 * sW[80 + f] + c2 * sW[160 + f] + sB[f];
        gg = gg > 0.f ? gg : 0.f;
        el += gg * sU[f];
        er += gg * sV[f];
    }
    el2[g * NN + n] = el;
    er2iv[((size_t)g * NN + n) * 2] = er;
}

// A[g][0..79] = sum_n q[n] * g1[n]  — register accumulation over 128-node LDS tiles.
#define RT 128
__global__ void k_r(const float* __restrict__ facc4, const float* __restrict__ W1,
                    const float* __restrict__ b1, const float* __restrict__ q,
                    float* __restrict__ A) {
    __shared__ float4 sF[RT];
    __shared__ float sQ[RT];
    __shared__ float sW[240], sB[80];
    __shared__ float sA[240];
    int t = threadIdx.x;
    for (int i = t; i < 80; i += 256) {
        sW[i] = W1[i];
        sW[80 + i] = W1[160 + i];
        sW[160 + i] = W1[320 + i];
        sB[i] = b1[i];
    }
    int g = blockIdx.y;
    int grp = t / 80, f = t - grp * 80;
    float acc = 0.f;
    for (int n0 = blockIdx.x * RT; n0 < NN; n0 += gridDim.x * RT) {
        __syncthreads();
        if (t < RT) {
            int n = n0 + t;
            sF[t] = (n < NN) ? *(const float4*)(facc4 + ((size_t)g * NN + n) * 4)
                             : make_float4(0.f, 0.f, 0.f, 0.f);
        } else if (t < 2 * RT) {
            int n = n0 + t - RT;
            sQ[t - RT] = (n < NN) ? q[g * NN + n] : 0.f;
        }
        __syncthreads();
        if (grp < 3) {
            for (int i = grp; i < RT; i += 3) {
                float qn = sQ[i];
                if (qn == 0.f) continue;
                float4 fa = sF[i];
                float inv = fa.w != 0.f ? 1.f / fa.w : 0.f;
                float c0 = fa.x * inv, c1 = fa.y * inv, c2 = fa.z * inv;
                float gg = c0 * sW[f] + c1 * sW[80 + f] + c2 * sW[160 + f] + sB[f];
                gg = gg > 0.f ? gg : 0.f;
                acc += qn * gg;
            }
        }
    }
    if (grp < 3) sA[t] = acc;
    __syncthreads();
    if (t < 80) atomicAdd(&A[g * 80 + t], sA[t] + sA[80 + t] + sA[160 + t]);
}

// Final head (+ image conv tail). 256 threads.
__global__ void k_final(const float* __restrict__ A, const float* __restrict__ W2g,
                        const float* __restrict__ b2, const float* __restrict__ Wg1,
                        const float* __restrict__ bg1, const float* __restrict__ emb_acc,
                        const float* __restrict__ Wc1, const float* __restrict__ Wc2,
                        const float* __restrict__ vocab, const float* __restrict__ W2f,
                        const float* __restrict__ W3, float* __restrict__ out, int out_size) {
    __shared__ float emb[60];
    __shared__ float hh[80 * 30];
    __shared__ float a[60];
    __shared__ float hc[70];
    __shared__ float tt[80];
    __shared__ float lp[2];
    int t = threadIdx.x;  // 256
    if (t < 60) {
        emb[t] = emb_acc[t];
        int i = t / 30, j = t % 30;
        float acc = 0.f;
        for (int f = 0; f < 80; ++f) acc += A[i * 80 + f] * W2g[f * 60 + j];
        a[t] = acc * (1.f / NN) + b2[j];
    }
    __syncthreads();
    for (int p = t; p < 2400; p += 256) {
        int i = p / 30, j = p % 30;
        float v = Wc1[i * 2 + 0] * emb[j] + Wc1[i * 2 + 1] * emb[30 + j];
        hh[p] = lrelu(v, 0.01f);
    }
    __syncthreads();
    if (t < 30) {
        float acc = 0.f;
        for (int i = 0; i < 80; ++i) acc += Wc2[i] * hh[i * 30 + t];
        hc[30 + t] = lrelu(acc, 0.01f);  // h2
        float acg = bg1[t];
        for (int j = 0; j < 60; ++j) acg += a[j] * Wg1[j * 30 + t];
        hc[t] = acg;
        if (t < 10) hc[60 + t] = vocab[t];
    }
    __syncthreads();
    if (t < 80) {
        float acc = 0.f;
        for (int qd = 0; qd < 70; ++qd) acc += hc[qd] * W2f[qd * 80 + t];
        tt[t] = acc;
    }
    __syncthreads();
    if (t < 2) {
        float acc = 0.f;
        for (int p = 0; p < 80; ++p) acc += tt[p] * W3[p * 2 + t];
        lp[t] = acc;
    }
    __syncthreads();
    if (t == 0) {
        float m = fmaxf(lp[0], lp[1]);
        float lse = m + logf(expf(lp[0] - m) + expf(lp[1] - m));
        out[0] = lp[0] - lse;
        out[1] = lp[1] - lse;
    }
    for (int i = 2 + t; i < out_size; i += blockDim.x) out[i] = 0.f;
}

extern "C" void kernel_launch(void* const* d_in, const int* in_sizes, int n_in,
                              void* d_out, int out_size, void* d_ws, size_t ws_size,
                              hipStream_t stream) {
    const float* x        = (const float*)d_in[0];
    const float* vocab    = (const float*)d_in[1];
    const float* nodef    = (const float*)d_in[2];
    const int*   src      = (const int*)d_in[3];
    const int*   dst      = (const int*)d_in[4];
    const float* W_lin1   = (const float*)d_in[5];
    const float* Wc1      = (const float*)d_in[6];
    const float* Wc2      = (const float*)d_in[7];
    const float* gat1_W   = (const float*)d_in[8];
    const float* gat1_al  = (const float*)d_in[9];
    const float* gat1_ar  = (const float*)d_in[10];
    const float* gat1_b   = (const float*)d_in[11];
    const float* gat2_W   = (const float*)d_in[12];
    const float* gat2_al  = (const float*)d_in[13];
    const float* gat2_ar  = (const float*)d_in[14];
    const float* gat2_b   = (const float*)d_in[15];
    const float* Wg1      = (const float*)d_in[16];
    const float* bg1      = (const float*)d_in[17];
    const float* W2       = (const float*)d_in[18];
    const float* W3       = (const float*)d_in[19];
    (void)in_sizes; (void)n_in; (void)ws_size;

    float* w = (float*)d_ws;
    size_t off = 0;
    auto alloc = [&](size_t n) { size_t o = off; off += (n + 63) & ~(size_t)63; return o; };
    size_t o_emb  = alloc(64);   // zeroed
    size_t o_A    = alloc(192);  // zeroed (contiguous with o_emb)
    size_t o_feat = alloc((size_t)2 * NN * 4);
    size_t o_er1  = alloc(2 * NN);
    size_t o_el2  = alloc(2 * NN);
    size_t o_eriv = alloc((size_t)2 * NN * 2);
    size_t o_facc = alloc((size_t)2 * NN * 4);
    size_t o_q    = alloc(2 * NN);
    size_t o_s16  = alloc((size_t)2 * NE / 2);  // 2*NE ushorts
    size_t o_d16  = alloc((size_t)2 * NE / 2);
    size_t o_P    = alloc((size_t)2 * C1 * NB1 * CH1 * 4);  // 25.6 MB
    u16* src16 = (u16*)(w + o_s16);
    u16* dst16 = (u16*)(w + o_d16);

    hipMemsetAsync(w + o_emb, 0, 256 * sizeof(float), stream);
    int cvt_blocks = (2 * 2 * NE / 8 + 255) / 256;
    k_pre<<<456 + cvt_blocks, 256, 0, stream>>>(x, W_lin1, nodef, gat1_W, gat1_al, gat1_ar,
                                                src, dst, w + o_emb, w + o_feat, w + o_er1,
                                                src16, dst16);

    k_e1c<<<dim3(NB1, C1, 2), 1024, 0, stream>>>(src16, dst16, w + o_feat, w + o_er1, w + o_P);
    k_n1r<<<dim3((NN + 255) / 256, 2), 256, 0, stream>>>(w + o_P, gat1_W, gat1_b, gat2_W,
                                                         gat2_al, gat2_ar, w + o_facc,
                                                         w + o_el2, w + o_eriv);

    k_e2c<<<dim3(NB2, C2, 2), 1024, 0, stream>>>(src16, dst16, w + o_el2, w + o_eriv, w + o_P);
    k_red<<<(2 * NN + 1023) / 1024, 1024, 0, stream>>>(w + o_P, w + o_eriv,
                                                       C2, NB2, CH2, 1, 2, 1);

    k_e3c<<<dim3(NB2, C2, 2), 1024, 0, stream>>>(src16, dst16, w + o_el2, w + o_eriv, w + o_P);
    k_red<<<(2 * NN + 1023) / 1024, 1024, 0, stream>>>(w + o_P, w + o_q,
                                                       C2, NB2, CH2, 0, 1, 0);

    k_r<<<dim3(128, 2), 256, 0, stream>>>(w + o_facc, gat1_W, gat1_b, w + o_q, w + o_A);
    k_final<<<1, 256, 0, stream>>>(w + o_A, gat2_W, gat2_b, Wg1, bg1, w + o_emb,
                                   Wc1, Wc2, vocab, W2, W3, (float*)d_out, out_size);
}